// Round 7
// baseline (381.714 us; speedup 1.0000x reference)
//
#include <hip/hip_runtime.h>
#include <math.h>

#define NN 50000
#define CIN 32
#define HD  64
#define NE  800000
#define NB  4
#define NBLK 196    // ceil(NN/256) scan blocks
#define NTILE 12500 // 200000 pairs / 16
#define TPB   3125  // tiles per batch (NN/16)
#define DWAVES 2048 // dense kernels: 512 blocks * 4 waves

typedef unsigned int uint32;
typedef unsigned short ushort_t;
typedef __attribute__((ext_vector_type(8))) short bf16x8;
typedef __attribute__((ext_vector_type(4))) float f32x4;

// ---- bf16 pack/unpack helpers (RNE) ----
__device__ __forceinline__ uint32 pk2(float a, float b) {
    uint32 ua = __float_as_uint(a), ub = __float_as_uint(b);
    uint32 ra = (ua + 0x7FFFu + ((ua >> 16) & 1u)) >> 16;
    uint32 rb = (ub + 0x7FFFu + ((ub >> 16) & 1u)) >> 16;
    return ra | (rb << 16);
}
__device__ __forceinline__ ushort_t b1(float v) {
    uint32 u = __float_as_uint(v);
    return (ushort_t)((u + 0x7FFFu + ((u >> 16) & 1u)) >> 16);
}
__device__ __forceinline__ float blo(uint32 v) { return __uint_as_float(v << 16); }
__device__ __forceinline__ float bhi(uint32 v) { return __uint_as_float(v & 0xFFFF0000u); }
__device__ __forceinline__ float sigm(float v) { return 1.0f / (1.0f + __expf(-v)); }

// ================= prepass =================

__global__ void k_init(float* __restrict__ deg, int* __restrict__ counts) {
    int i = blockIdx.x * blockDim.x + threadIdx.x;
    if (i < NN) { deg[i] = 1.0f; counts[i] = 0; }
}

// Fused: weight prepack + bf16 feature staging + degree/count accumulation.
// F[n][192 u32] record: j in [0,64): x (b=j>>4, ch-pair j&15); j in [64,192): h
// (j'=j-64, b=j'>>5, ch-pair j'&31).
__global__ void k_pre(const float* __restrict__ x, const float* __restrict__ h,
                      const int* __restrict__ ei, const float* __restrict__ ew,
                      const float* __restrict__ Wuz, const float* __restrict__ Whz,
                      const float* __restrict__ Wur, const float* __restrict__ Whr,
                      const float* __restrict__ Wuh, const float* __restrict__ Whh,
                      const float* __restrict__ buz, const float* __restrict__ bhz,
                      const float* __restrict__ bur, const float* __restrict__ bhr,
                      const float* __restrict__ buh, const float* __restrict__ bhh,
                      uint32* __restrict__ F, float* __restrict__ deg,
                      int* __restrict__ counts,
                      uint32* __restrict__ WB, float* __restrict__ BS) {
    int stride = gridDim.x * blockDim.x;
    int tid = blockIdx.x * blockDim.x + threadIdx.x;

    // weight frags (same (lane,elem)->k bijection as the A packing)
    if (tid < 9216) {
        int g = tid / 3072, rem = tid - g * 3072;
        int kt = rem >> 10, r2 = rem & 1023;
        int ct = r2 >> 8, r3 = r2 & 255;
        int l = r3 >> 2, jp = r3 & 3;
        int k = kt * 32 + ((l >> 4) << 3) + 2 * jp;
        int ch = ct * 16 + (l & 15);
        const float* Wu = (g == 0) ? Wuz : (g == 1) ? Wur : Wuh;
        const float* Wh = (g == 0) ? Whz : (g == 1) ? Whr : Whh;
        float w0 = (k < 32) ? Wu[k * 64 + ch] : Wh[(k - 32) * 64 + ch];
        int k1 = k + 1;
        float w1 = (k1 < 32) ? Wu[k1 * 64 + ch] : Wh[(k1 - 32) * 64 + ch];
        WB[tid] = pk2(w0, w1);
    }
    if (tid < 192) {
        int g = tid >> 6, c = tid & 63;
        const float* bu = (g == 0) ? buz : (g == 1) ? bur : buh;
        const float* bh = (g == 0) ? bhz : (g == 1) ? bhr : bhh;
        BS[tid] = bu[c] + bh[c];
    }

    for (int t = tid; t < NB * NN * (CIN / 2); t += stride) {
        int cp = t & 15; int rest = t >> 4;
        int b = rest / NN; int n = rest - b * NN;
        float2 v = *(const float2*)&x[(b * NN + n) * CIN + 2 * cp];
        F[n * 192 + b * 16 + cp] = pk2(v.x, v.y);
    }
    for (int t = tid; t < NB * NN * (HD / 2); t += stride) {
        int cp = t & 31; int rest = t >> 5;
        int b = rest / NN; int n = rest - b * NN;
        float2 v = *(const float2*)&h[(b * NN + n) * HD + 2 * cp];
        F[n * 192 + 64 + b * 32 + cp] = pk2(v.x, v.y);
    }
    for (int e = tid; e < NE; e += stride) {
        int d = ei[NE + e];
        atomicAdd(&deg[d], ew[e]);
        atomicAdd(&counts[d], 1);
    }
}

// ---- exclusive scan of counts -> rowptr, cursor; dinv ----

__global__ void k_scan1(const int* __restrict__ counts, int* __restrict__ tmp,
                        int* __restrict__ partials) {
    __shared__ int lds[256];
    int i = blockIdx.x * 256 + threadIdx.x;
    int v = (i < NN) ? counts[i] : 0;
    lds[threadIdx.x] = v;
    __syncthreads();
    for (int off = 1; off < 256; off <<= 1) {
        int t = (threadIdx.x >= off) ? lds[threadIdx.x - off] : 0;
        __syncthreads();
        lds[threadIdx.x] += t;
        __syncthreads();
    }
    if (i < NN) tmp[i] = lds[threadIdx.x];
    if (threadIdx.x == 255) partials[blockIdx.x] = lds[255];
}

__global__ void k_scan2(int* __restrict__ partials) {
    __shared__ int lds[256];
    int v = (threadIdx.x < NBLK) ? partials[threadIdx.x] : 0;
    lds[threadIdx.x] = v;
    __syncthreads();
    for (int off = 1; off < 256; off <<= 1) {
        int t = (threadIdx.x >= off) ? lds[threadIdx.x - off] : 0;
        __syncthreads();
        lds[threadIdx.x] += t;
        __syncthreads();
    }
    int ex = (threadIdx.x > 0) ? lds[threadIdx.x - 1] : 0;
    if (threadIdx.x < NBLK) partials[threadIdx.x] = ex;
}

__global__ void k_scan3(const int* __restrict__ tmp, const int* __restrict__ counts,
                        const int* __restrict__ partials,
                        int* __restrict__ rowptr, int* __restrict__ cursor,
                        float* __restrict__ deg) {
    int i = blockIdx.x * blockDim.x + threadIdx.x;
    if (i < NN) {
        int inc = tmp[i] + partials[i >> 8];
        rowptr[i + 1] = inc;
        cursor[i] = inc - counts[i];
        if (i == 0) rowptr[0] = 0;
        float dg = deg[i];
        deg[i] = (dg > 0.0f) ? rsqrtf(fmaxf(dg, 1e-12f)) : 0.0f;
    }
}

__global__ void k_bucket(const int* __restrict__ ei, const float* __restrict__ ew,
                         const float* __restrict__ dinv,
                         int* __restrict__ cursor, int2* __restrict__ eb) {
    int stride = gridDim.x * blockDim.x;
    for (int e = blockIdx.x * blockDim.x + threadIdx.x; e < NE; e += stride) {
        int s = ei[e], d = ei[NE + e];
        float nrm = dinv[s] * ew[e] * dinv[d];
        int pos = atomicAdd(&cursor[d], 1);
        eb[pos] = make_int2(s, __float_as_int(nrm));
    }
}

// ================= gathers =================
// one wave per dst node; lane l covers u32 slots 3l..3l+2 of the 192-u32 record.
// Agg layout == F layout (node-major), so writes are 3 consecutive dwords.

__global__ __launch_bounds__(256) void k_gather_xh(
    const int* __restrict__ rowptr, const int2* __restrict__ eb,
    const float* __restrict__ dinv, const uint32* __restrict__ F,
    uint32* __restrict__ AggU) {

    int l = threadIdx.x & 63;
    int d = __builtin_amdgcn_readfirstlane(blockIdx.x * 4 + (threadIdx.x >> 6));
    float dv = dinv[d];
    float s2 = dv * dv;

    const uint32* fp = F + 3 * l;
    const uint32* sp = fp + d * 192;
    uint32 u0 = sp[0], u1 = sp[1], u2 = sp[2];
    float a0 = s2 * blo(u0), a1 = s2 * bhi(u0);
    float a2 = s2 * blo(u1), a3 = s2 * bhi(u1);
    float a4 = s2 * blo(u2), a5 = s2 * bhi(u2);

    int e  = rowptr[d];
    int e1 = rowptr[d + 1];

    for (; e + 7 < e1; e += 8) {
        int2 p0 = eb[e],     p1 = eb[e + 1], p2 = eb[e + 2], p3 = eb[e + 3];
        int2 p4 = eb[e + 4], p5 = eb[e + 5], p6 = eb[e + 6], p7 = eb[e + 7];
        const uint32* q0 = fp + p0.x * 192;
        const uint32* q1 = fp + p1.x * 192;
        const uint32* q2 = fp + p2.x * 192;
        const uint32* q3 = fp + p3.x * 192;
        const uint32* q4 = fp + p4.x * 192;
        const uint32* q5 = fp + p5.x * 192;
        const uint32* q6 = fp + p6.x * 192;
        const uint32* q7 = fp + p7.x * 192;
        uint32 v00 = q0[0], v01 = q0[1], v02 = q0[2];
        uint32 v10 = q1[0], v11 = q1[1], v12 = q1[2];
        uint32 v20 = q2[0], v21 = q2[1], v22 = q2[2];
        uint32 v30 = q3[0], v31 = q3[1], v32 = q3[2];
        uint32 v40 = q4[0], v41 = q4[1], v42 = q4[2];
        uint32 v50 = q5[0], v51 = q5[1], v52 = q5[2];
        uint32 v60 = q6[0], v61 = q6[1], v62 = q6[2];
        uint32 v70 = q7[0], v71 = q7[1], v72 = q7[2];
        float n0 = __int_as_float(p0.y), n1 = __int_as_float(p1.y);
        float n2 = __int_as_float(p2.y), n3 = __int_as_float(p3.y);
        float n4 = __int_as_float(p4.y), n5 = __int_as_float(p5.y);
        float n6 = __int_as_float(p6.y), n7 = __int_as_float(p7.y);
        a0 = fmaf(n0, blo(v00), a0); a1 = fmaf(n0, bhi(v00), a1);
        a2 = fmaf(n0, blo(v01), a2); a3 = fmaf(n0, bhi(v01), a3);
        a4 = fmaf(n0, blo(v02), a4); a5 = fmaf(n0, bhi(v02), a5);
        a0 = fmaf(n1, blo(v10), a0); a1 = fmaf(n1, bhi(v10), a1);
        a2 = fmaf(n1, blo(v11), a2); a3 = fmaf(n1, bhi(v11), a3);
        a4 = fmaf(n1, blo(v12), a4); a5 = fmaf(n1, bhi(v12), a5);
        a0 = fmaf(n2, blo(v20), a0); a1 = fmaf(n2, bhi(v20), a1);
        a2 = fmaf(n2, blo(v21), a2); a3 = fmaf(n2, bhi(v21), a3);
        a4 = fmaf(n2, blo(v22), a4); a5 = fmaf(n2, bhi(v22), a5);
        a0 = fmaf(n3, blo(v30), a0); a1 = fmaf(n3, bhi(v30), a1);
        a2 = fmaf(n3, blo(v31), a2); a3 = fmaf(n3, bhi(v31), a3);
        a4 = fmaf(n3, blo(v32), a4); a5 = fmaf(n3, bhi(v32), a5);
        a0 = fmaf(n4, blo(v40), a0); a1 = fmaf(n4, bhi(v40), a1);
        a2 = fmaf(n4, blo(v41), a2); a3 = fmaf(n4, bhi(v41), a3);
        a4 = fmaf(n4, blo(v42), a4); a5 = fmaf(n4, bhi(v42), a5);
        a0 = fmaf(n5, blo(v50), a0); a1 = fmaf(n5, bhi(v50), a1);
        a2 = fmaf(n5, blo(v51), a2); a3 = fmaf(n5, bhi(v51), a3);
        a4 = fmaf(n5, blo(v52), a4); a5 = fmaf(n5, bhi(v52), a5);
        a0 = fmaf(n6, blo(v60), a0); a1 = fmaf(n6, bhi(v60), a1);
        a2 = fmaf(n6, blo(v61), a2); a3 = fmaf(n6, bhi(v61), a3);
        a4 = fmaf(n6, blo(v62), a4); a5 = fmaf(n6, bhi(v62), a5);
        a0 = fmaf(n7, blo(v70), a0); a1 = fmaf(n7, bhi(v70), a1);
        a2 = fmaf(n7, blo(v71), a2); a3 = fmaf(n7, bhi(v71), a3);
        a4 = fmaf(n7, blo(v72), a4); a5 = fmaf(n7, bhi(v72), a5);
    }
    for (; e + 3 < e1; e += 4) {
        int2 p0 = eb[e], p1 = eb[e + 1], p2 = eb[e + 2], p3 = eb[e + 3];
        const uint32* q0 = fp + p0.x * 192;
        const uint32* q1 = fp + p1.x * 192;
        const uint32* q2 = fp + p2.x * 192;
        const uint32* q3 = fp + p3.x * 192;
        uint32 v00 = q0[0], v01 = q0[1], v02 = q0[2];
        uint32 v10 = q1[0], v11 = q1[1], v12 = q1[2];
        uint32 v20 = q2[0], v21 = q2[1], v22 = q2[2];
        uint32 v30 = q3[0], v31 = q3[1], v32 = q3[2];
        float n0 = __int_as_float(p0.y), n1 = __int_as_float(p1.y);
        float n2 = __int_as_float(p2.y), n3 = __int_as_float(p3.y);
        a0 = fmaf(n0, blo(v00), a0); a1 = fmaf(n0, bhi(v00), a1);
        a2 = fmaf(n0, blo(v01), a2); a3 = fmaf(n0, bhi(v01), a3);
        a4 = fmaf(n0, blo(v02), a4); a5 = fmaf(n0, bhi(v02), a5);
        a0 = fmaf(n1, blo(v10), a0); a1 = fmaf(n1, bhi(v10), a1);
        a2 = fmaf(n1, blo(v11), a2); a3 = fmaf(n1, bhi(v11), a3);
        a4 = fmaf(n1, blo(v12), a4); a5 = fmaf(n1, bhi(v12), a5);
        a0 = fmaf(n2, blo(v20), a0); a1 = fmaf(n2, bhi(v20), a1);
        a2 = fmaf(n2, blo(v21), a2); a3 = fmaf(n2, bhi(v21), a3);
        a4 = fmaf(n2, blo(v22), a4); a5 = fmaf(n2, bhi(v22), a5);
        a0 = fmaf(n3, blo(v30), a0); a1 = fmaf(n3, bhi(v30), a1);
        a2 = fmaf(n3, blo(v31), a2); a3 = fmaf(n3, bhi(v31), a3);
        a4 = fmaf(n3, blo(v32), a4); a5 = fmaf(n3, bhi(v32), a5);
    }
    for (; e < e1; ++e) {
        int2 p0 = eb[e];
        const uint32* q0 = fp + p0.x * 192;
        uint32 v00 = q0[0], v01 = q0[1], v02 = q0[2];
        float n0 = __int_as_float(p0.y);
        a0 = fmaf(n0, blo(v00), a0); a1 = fmaf(n0, bhi(v00), a1);
        a2 = fmaf(n0, blo(v01), a2); a3 = fmaf(n0, bhi(v01), a3);
        a4 = fmaf(n0, blo(v02), a4); a5 = fmaf(n0, bhi(v02), a5);
    }

    uint32* op = AggU + d * 192 + 3 * l;
    op[0] = pk2(a0, a1);
    op[1] = pk2(a2, a3);
    op[2] = pk2(a4, a5);
}

// rh record R[n][128 u32] (bf16 slot = b*64 + ch), lane l covers u32 slots 2l,2l+1.
// writes Arh bf16 into Agg h-region (node-major): u32 slot d*192 + 64 + b*32 + cp
__global__ __launch_bounds__(256) void k_gather_rh(
    const int* __restrict__ rowptr, const int2* __restrict__ eb,
    const float* __restrict__ dinv, const uint32* __restrict__ R,
    uint32* __restrict__ AggU) {

    int l = threadIdx.x & 63;
    int d = __builtin_amdgcn_readfirstlane(blockIdx.x * 4 + (threadIdx.x >> 6));
    float dv = dinv[d];
    float s2 = dv * dv;

    const uint32* rp = R + 2 * l;
    uint2 sv = *(const uint2*)(rp + d * 128);
    float a0 = s2 * blo(sv.x), a1 = s2 * bhi(sv.x);
    float a2 = s2 * blo(sv.y), a3 = s2 * bhi(sv.y);

    int e  = rowptr[d];
    int e1 = rowptr[d + 1];

    for (; e + 7 < e1; e += 8) {
        int2 p0 = eb[e],     p1 = eb[e + 1], p2 = eb[e + 2], p3 = eb[e + 3];
        int2 p4 = eb[e + 4], p5 = eb[e + 5], p6 = eb[e + 6], p7 = eb[e + 7];
        uint2 v0 = *(const uint2*)(rp + p0.x * 128);
        uint2 v1 = *(const uint2*)(rp + p1.x * 128);
        uint2 v2 = *(const uint2*)(rp + p2.x * 128);
        uint2 v3 = *(const uint2*)(rp + p3.x * 128);
        uint2 v4 = *(const uint2*)(rp + p4.x * 128);
        uint2 v5 = *(const uint2*)(rp + p5.x * 128);
        uint2 v6 = *(const uint2*)(rp + p6.x * 128);
        uint2 v7 = *(const uint2*)(rp + p7.x * 128);
        float n0 = __int_as_float(p0.y), n1 = __int_as_float(p1.y);
        float n2 = __int_as_float(p2.y), n3 = __int_as_float(p3.y);
        float n4 = __int_as_float(p4.y), n5 = __int_as_float(p5.y);
        float n6 = __int_as_float(p6.y), n7 = __int_as_float(p7.y);
        a0 = fmaf(n0, blo(v0.x), a0); a1 = fmaf(n0, bhi(v0.x), a1);
        a2 = fmaf(n0, blo(v0.y), a2); a3 = fmaf(n0, bhi(v0.y), a3);
        a0 = fmaf(n1, blo(v1.x), a0); a1 = fmaf(n1, bhi(v1.x), a1);
        a2 = fmaf(n1, blo(v1.y), a2); a3 = fmaf(n1, bhi(v1.y), a3);
        a0 = fmaf(n2, blo(v2.x), a0); a1 = fmaf(n2, bhi(v2.x), a1);
        a2 = fmaf(n2, blo(v2.y), a2); a3 = fmaf(n2, bhi(v2.y), a3);
        a0 = fmaf(n3, blo(v3.x), a0); a1 = fmaf(n3, bhi(v3.x), a1);
        a2 = fmaf(n3, blo(v3.y), a2); a3 = fmaf(n3, bhi(v3.y), a3);
        a0 = fmaf(n4, blo(v4.x), a0); a1 = fmaf(n4, bhi(v4.x), a1);
        a2 = fmaf(n4, blo(v4.y), a2); a3 = fmaf(n4, bhi(v4.y), a3);
        a0 = fmaf(n5, blo(v5.x), a0); a1 = fmaf(n5, bhi(v5.x), a1);
        a2 = fmaf(n5, blo(v5.y), a2); a3 = fmaf(n5, bhi(v5.y), a3);
        a0 = fmaf(n6, blo(v6.x), a0); a1 = fmaf(n6, bhi(v6.x), a1);
        a2 = fmaf(n6, blo(v6.y), a2); a3 = fmaf(n6, bhi(v6.y), a3);
        a0 = fmaf(n7, blo(v7.x), a0); a1 = fmaf(n7, bhi(v7.x), a1);
        a2 = fmaf(n7, blo(v7.y), a2); a3 = fmaf(n7, bhi(v7.y), a3);
    }
    for (; e + 3 < e1; e += 4) {
        int2 p0 = eb[e], p1 = eb[e + 1], p2 = eb[e + 2], p3 = eb[e + 3];
        uint2 v0 = *(const uint2*)(rp + p0.x * 128);
        uint2 v1 = *(const uint2*)(rp + p1.x * 128);
        uint2 v2 = *(const uint2*)(rp + p2.x * 128);
        uint2 v3 = *(const uint2*)(rp + p3.x * 128);
        float n0 = __int_as_float(p0.y), n1 = __int_as_float(p1.y);
        float n2 = __int_as_float(p2.y), n3 = __int_as_float(p3.y);
        a0 = fmaf(n0, blo(v0.x), a0); a1 = fmaf(n0, bhi(v0.x), a1);
        a2 = fmaf(n0, blo(v0.y), a2); a3 = fmaf(n0, bhi(v0.y), a3);
        a0 = fmaf(n1, blo(v1.x), a0); a1 = fmaf(n1, bhi(v1.x), a1);
        a2 = fmaf(n1, blo(v1.y), a2); a3 = fmaf(n1, bhi(v1.y), a3);
        a0 = fmaf(n2, blo(v2.x), a0); a1 = fmaf(n2, bhi(v2.x), a1);
        a2 = fmaf(n2, blo(v2.y), a2); a3 = fmaf(n2, bhi(v2.y), a3);
        a0 = fmaf(n3, blo(v3.x), a0); a1 = fmaf(n3, bhi(v3.x), a1);
        a2 = fmaf(n3, blo(v3.y), a2); a3 = fmaf(n3, bhi(v3.y), a3);
    }
    for (; e < e1; ++e) {
        int2 p0 = eb[e];
        uint2 v0 = *(const uint2*)(rp + p0.x * 128);
        float n0 = __int_as_float(p0.y);
        a0 = fmaf(n0, blo(v0.x), a0); a1 = fmaf(n0, bhi(v0.x), a1);
        a2 = fmaf(n0, blo(v0.y), a2); a3 = fmaf(n0, bhi(v0.y), a3);
    }

    *(uint2*)&AggU[d * 192 + 64 + (l >> 4) * 32 + ((2 * l) & 31)] =
        make_uint2(pk2(a0, a1), pk2(a2, a3));
}

// ================= dense kernels (MFMA, weights in registers, grid-stride) =================

__global__ __launch_bounds__(256) void k_zr(
    const uint32* __restrict__ AggU, const float* __restrict__ h,
    const uint32* __restrict__ WB, const float* __restrict__ BS,
    float* __restrict__ z_out, ushort_t* __restrict__ R16) {

    int l  = threadIdx.x & 63;
    int wv = blockIdx.x * 4 + (threadIdx.x >> 6);    // 0..DWAVES-1
    int lr = l & 15, lg = l >> 4;

    const bf16x8* wz = (const bf16x8*)WB;
    const bf16x8* wr = (const bf16x8*)(WB + 3072);
    bf16x8 wzf[12], wrf[12];
    #pragma unroll
    for (int f = 0; f < 12; ++f) { wzf[f] = wz[f * 64 + l]; wrf[f] = wr[f * 64 + l]; }
    float bz[4], br[4];
    #pragma unroll
    for (int ct = 0; ct < 4; ++ct) {
        bz[ct] = BS[ct * 16 + lr];
        br[ct] = BS[64 + ct * 16 + lr];
    }

    for (int t = wv; t < NTILE; t += DWAVES) {
        int bb = t / TPB, nt = t - bb * TPB;
        const uint32* base = AggU + (nt * 16 + lr) * 192;
        bf16x8 af0 = *(const bf16x8*)(base + bb * 16 + lg * 4);
        bf16x8 af1 = *(const bf16x8*)(base + 64 + bb * 32 + lg * 4);
        bf16x8 af2 = *(const bf16x8*)(base + 64 + bb * 32 + 16 + lg * 4);

        f32x4 az[4], ar[4];
        #pragma unroll
        for (int c = 0; c < 4; ++c) { az[c] = (f32x4){0,0,0,0}; ar[c] = (f32x4){0,0,0,0}; }

        #pragma unroll
        for (int ct = 0; ct < 4; ++ct) {
            az[ct] = __builtin_amdgcn_mfma_f32_16x16x32_bf16(af0, wzf[0*4+ct], az[ct], 0,0,0);
            ar[ct] = __builtin_amdgcn_mfma_f32_16x16x32_bf16(af0, wrf[0*4+ct], ar[ct], 0,0,0);
            az[ct] = __builtin_amdgcn_mfma_f32_16x16x32_bf16(af1, wzf[1*4+ct], az[ct], 0,0,0);
            ar[ct] = __builtin_amdgcn_mfma_f32_16x16x32_bf16(af1, wrf[1*4+ct], ar[ct], 0,0,0);
            az[ct] = __builtin_amdgcn_mfma_f32_16x16x32_bf16(af2, wzf[2*4+ct], az[ct], 0,0,0);
            ar[ct] = __builtin_amdgcn_mfma_f32_16x16x32_bf16(af2, wrf[2*4+ct], ar[ct], 0,0,0);
        }

        int node0 = nt * 16;
        #pragma unroll
        for (int ct = 0; ct < 4; ++ct) {
            int ch = ct * 16 + lr;
            #pragma unroll
            for (int rr = 0; rr < 4; ++rr) {
                int node = node0 + lg * 4 + rr;
                int off  = (bb * NN + node) * 64 + ch;
                float zv = sigm(az[ct][rr] + bz[ct]);
                float rv = sigm(ar[ct][rr] + br[ct]);
                float hv = h[off];
                z_out[off] = zv;
                R16[node * 256 + bb * 64 + ch] = b1(rv * hv);
            }
        }
    }
}

__global__ __launch_bounds__(256) void k_final(
    const uint32* __restrict__ AggU, const float* __restrict__ h,
    const uint32* __restrict__ WB, const float* __restrict__ BS,
    float* __restrict__ out) {

    int l  = threadIdx.x & 63;
    int wv = blockIdx.x * 4 + (threadIdx.x >> 6);
    int lr = l & 15, lg = l >> 4;

    const bf16x8* wh = (const bf16x8*)(WB + 6144);
    bf16x8 whf[12];
    #pragma unroll
    for (int f = 0; f < 12; ++f) whf[f] = wh[f * 64 + l];
    float bs[4];
    #pragma unroll
    for (int ct = 0; ct < 4; ++ct) bs[ct] = BS[128 + ct * 16 + lr];

    for (int t = wv; t < NTILE; t += DWAVES) {
        int bb = t / TPB, nt = t - bb * TPB;
        const uint32* base = AggU + (nt * 16 + lr) * 192;
        bf16x8 af0 = *(const bf16x8*)(base + bb * 16 + lg * 4);
        bf16x8 af1 = *(const bf16x8*)(base + 64 + bb * 32 + lg * 4);
        bf16x8 af2 = *(const bf16x8*)(base + 64 + bb * 32 + 16 + lg * 4);

        f32x4 ac[4];
        #pragma unroll
        for (int c = 0; c < 4; ++c) ac[c] = (f32x4){0,0,0,0};

        #pragma unroll
        for (int ct = 0; ct < 4; ++ct) {
            ac[ct] = __builtin_amdgcn_mfma_f32_16x16x32_bf16(af0, whf[0*4+ct], ac[ct], 0,0,0);
            ac[ct] = __builtin_amdgcn_mfma_f32_16x16x32_bf16(af1, whf[1*4+ct], ac[ct], 0,0,0);
            ac[ct] = __builtin_amdgcn_mfma_f32_16x16x32_bf16(af2, whf[2*4+ct], ac[ct], 0,0,0);
        }

        int node0 = nt * 16;
        #pragma unroll
        for (int ct = 0; ct < 4; ++ct) {
            int ch = ct * 16 + lr;
            #pragma unroll
            for (int rr = 0; rr < 4; ++rr) {
                int node = node0 + lg * 4 + rr;
                int off  = (bb * NN + node) * 64 + ch;
                float hh = tanhf(ac[ct][rr] + bs[ct]);
                float zv = out[off];
                float hv = h[off];
                out[off] = (1.0f - zv) * hv + zv * hh;
            }
        }
    }
}

// ================= host launch =================

extern "C" void kernel_launch(void* const* d_in, const int* in_sizes, int n_in,
                              void* d_out, int out_size, void* d_ws, size_t ws_size,
                              hipStream_t stream) {
    const float* x   = (const float*)d_in[0];
    const float* h   = (const float*)d_in[1];
    const int*   ei  = (const int*)d_in[2];
    const float* ew  = (const float*)d_in[3];
    const float* Wuz = (const float*)d_in[4];
    const float* buz = (const float*)d_in[5];
    const float* Whz = (const float*)d_in[6];
    const float* bhz = (const float*)d_in[7];
    const float* Wur = (const float*)d_in[8];
    const float* bur = (const float*)d_in[9];
    const float* Whr = (const float*)d_in[10];
    const float* bhr = (const float*)d_in[11];
    const float* Wuh = (const float*)d_in[12];
    const float* buh = (const float*)d_in[13];
    const float* Whh = (const float*)d_in[14];
    const float* bhh = (const float*)d_in[15];
    float* out = (float*)d_out;

    // ws layout (4B words), total ~21.07M words = 84.3 MB
    float*  w      = (float*)d_ws;
    float*  dinv   = w;                               // 51,200
    int*    rowptr = (int*)(w + 51200);               // 51,200
    int2*   eb     = (int2*)(w + 102400);             // 1,600,000
    uint32* F      = (uint32*)(w + 1702400);          // 9,600,000 (dead after gather_xh)
    uint32* R      = F;                               // aliases F: NN*128 = 6,400,000
    uint32* AggU   = (uint32*)(w + 11302400);         // 9,600,000 (node-major, == F layout)
    uint32* WB     = (uint32*)(w + 20902400);         // 9,216
    float*  BS     = (float*)(w + 20911616);          // 192
    int*    counts = (int*)(w + 20911808);            // 51,200
    int*    tmp    = (int*)(w + 20963008);            // 51,200
    int*    cursor = (int*)(w + 21014208);            // 51,200
    int*    parts  = (int*)(w + 21065408);            // 256

    k_init<<<(NN + 255) / 256, 256, 0, stream>>>(dinv, counts);
    k_pre<<<2048, 256, 0, stream>>>(x, h, ei, ew,
                                    Wuz, Whz, Wur, Whr, Wuh, Whh,
                                    buz, bhz, bur, bhr, buh, bhh,
                                    F, dinv, counts, WB, BS);

    k_scan1<<<NBLK, 256, 0, stream>>>(counts, tmp, parts);
    k_scan2<<<1, 256, 0, stream>>>(parts);
    k_scan3<<<NBLK, 256, 0, stream>>>(tmp, counts, parts, rowptr, cursor, dinv);

    k_bucket<<<2048, 256, 0, stream>>>(ei, ew, dinv, cursor, eb);

    k_gather_xh<<<NN / 4, 256, 0, stream>>>(rowptr, eb, dinv, F, AggU);

    k_zr<<<DWAVES / 4, 256, 0, stream>>>(AggU, h, WB, BS, out, (ushort_t*)R);

    k_gather_rh<<<NN / 4, 256, 0, stream>>>(rowptr, eb, dinv, R, AggU);

    k_final<<<DWAVES / 4, 256, 0, stream>>>(AggU, h, WB, BS, out);
}

// Round 8
// 350.691 us; speedup vs baseline: 1.0885x; 1.0885x over previous
//
#include <hip/hip_runtime.h>
#include <math.h>

#define NN 50000
#define CIN 32
#define HD  64
#define NE  800000
#define NB  4
#define NBLK 196    // ceil(NN/256) scan blocks
#define NTILE 12500 // 200000 pairs / 16
#define TPB   3125  // tiles per batch (NN/16)
#define DWAVES 2048 // dense kernels: 512 blocks * 4 waves

typedef unsigned int uint32;
typedef unsigned short ushort_t;
typedef unsigned long long u64;
typedef __attribute__((ext_vector_type(8))) short bf16x8;
typedef __attribute__((ext_vector_type(4))) float f32x4;

// ---- bf16 pack/unpack helpers (RNE) ----
__device__ __forceinline__ uint32 pk2(float a, float b) {
    uint32 ua = __float_as_uint(a), ub = __float_as_uint(b);
    uint32 ra = (ua + 0x7FFFu + ((ua >> 16) & 1u)) >> 16;
    uint32 rb = (ub + 0x7FFFu + ((ub >> 16) & 1u)) >> 16;
    return ra | (rb << 16);
}
__device__ __forceinline__ ushort_t b1(float v) {
    uint32 u = __float_as_uint(v);
    return (ushort_t)((u + 0x7FFFu + ((u >> 16) & 1u)) >> 16);
}
__device__ __forceinline__ float ub(ushort_t v) {
    return __uint_as_float(((uint32)v) << 16);
}
__device__ __forceinline__ float blo(uint32 v) { return __uint_as_float(v << 16); }
__device__ __forceinline__ float bhi(uint32 v) { return __uint_as_float(v & 0xFFFF0000u); }
__device__ __forceinline__ float sigm(float v) { return 1.0f / (1.0f + __expf(-v)); }

// ================= prepass (pure streaming, no atomics) =================
// F[n][192 u32] record: j in [0,64): x (b=j>>4, ch-pair j&15); j in [64,192): h
// (j'=j-64, b=j'>>5, ch-pair j'&31). Also: degcnt init + weight prepack.

__global__ void k_prep(const float* __restrict__ x, const float* __restrict__ h,
                       const float* __restrict__ Wuz, const float* __restrict__ Whz,
                       const float* __restrict__ Wur, const float* __restrict__ Whr,
                       const float* __restrict__ Wuh, const float* __restrict__ Whh,
                       const float* __restrict__ buz, const float* __restrict__ bhz,
                       const float* __restrict__ bur, const float* __restrict__ bhr,
                       const float* __restrict__ buh, const float* __restrict__ bhh,
                       uint32* __restrict__ F, u64* __restrict__ degcnt,
                       uint32* __restrict__ WB, float* __restrict__ BS) {
    int stride = gridDim.x * blockDim.x;
    int tid = blockIdx.x * blockDim.x + threadIdx.x;

    if (tid < NN) degcnt[tid] = (1ull << 24);   // self-loop weight 1.0 fixed-point

    if (tid < 9216) {   // weight frags (same (lane,elem)->k bijection as A packing)
        int g = tid / 3072, rem = tid - g * 3072;
        int kt = rem >> 10, r2 = rem & 1023;
        int ct = r2 >> 8, r3 = r2 & 255;
        int l = r3 >> 2, jp = r3 & 3;
        int k = kt * 32 + ((l >> 4) << 3) + 2 * jp;
        int ch = ct * 16 + (l & 15);
        const float* Wu = (g == 0) ? Wuz : (g == 1) ? Wur : Wuh;
        const float* Wh = (g == 0) ? Whz : (g == 1) ? Whr : Whh;
        float w0 = (k < 32) ? Wu[k * 64 + ch] : Wh[(k - 32) * 64 + ch];
        int k1 = k + 1;
        float w1 = (k1 < 32) ? Wu[k1 * 64 + ch] : Wh[(k1 - 32) * 64 + ch];
        WB[tid] = pk2(w0, w1);
    }
    if (tid < 192) {
        int g = tid >> 6, c = tid & 63;
        const float* bu = (g == 0) ? buz : (g == 1) ? bur : buh;
        const float* bh = (g == 0) ? bhz : (g == 1) ? bhr : bhh;
        BS[tid] = bu[c] + bh[c];
    }

    for (int t = tid; t < NB * NN * (CIN / 2); t += stride) {
        int cp = t & 15; int rest = t >> 4;
        int b = rest / NN; int n = rest - b * NN;
        float2 v = *(const float2*)&x[(b * NN + n) * CIN + 2 * cp];
        F[n * 192 + b * 16 + cp] = pk2(v.x, v.y);
    }
    for (int t = tid; t < NB * NN * (HD / 2); t += stride) {
        int cp = t & 31; int rest = t >> 5;
        int b = rest / NN; int n = rest - b * NN;
        float2 v = *(const float2*)&h[(b * NN + n) * HD + 2 * cp];
        F[n * 192 + 64 + b * 32 + cp] = pk2(v.x, v.y);
    }
}

// one u64 atomic per edge: count in bits >=40, weight in 2^-24 fixed point low bits
__global__ void k_degcnt(const int* __restrict__ ei, const float* __restrict__ ew,
                         u64* __restrict__ degcnt) {
    int stride = gridDim.x * blockDim.x;
    for (int e = blockIdx.x * blockDim.x + threadIdx.x; e < NE; e += stride) {
        int d = ei[NE + e];
        u64 val = (1ull << 40) + (u64)(uint32)(ew[e] * 16777216.0f + 0.5f);
        atomicAdd(&degcnt[d], val);
    }
}

// ---- exclusive scan of counts -> rowptr, cursor; dinv ----

__global__ void k_scan1(const u64* __restrict__ degcnt, int* __restrict__ tmp,
                        int* __restrict__ partials) {
    __shared__ int lds[256];
    int i = blockIdx.x * 256 + threadIdx.x;
    int v = (i < NN) ? (int)(degcnt[i] >> 40) : 0;
    lds[threadIdx.x] = v;
    __syncthreads();
    for (int off = 1; off < 256; off <<= 1) {
        int t = (threadIdx.x >= off) ? lds[threadIdx.x - off] : 0;
        __syncthreads();
        lds[threadIdx.x] += t;
        __syncthreads();
    }
    if (i < NN) tmp[i] = lds[threadIdx.x];
    if (threadIdx.x == 255) partials[blockIdx.x] = lds[255];
}

__global__ void k_scan2(int* __restrict__ partials) {
    __shared__ int lds[256];
    int v = (threadIdx.x < NBLK) ? partials[threadIdx.x] : 0;
    lds[threadIdx.x] = v;
    __syncthreads();
    for (int off = 1; off < 256; off <<= 1) {
        int t = (threadIdx.x >= off) ? lds[threadIdx.x - off] : 0;
        __syncthreads();
        lds[threadIdx.x] += t;
        __syncthreads();
    }
    int ex = (threadIdx.x > 0) ? lds[threadIdx.x - 1] : 0;
    if (threadIdx.x < NBLK) partials[threadIdx.x] = ex;
}

__global__ void k_scan3(const int* __restrict__ tmp, const u64* __restrict__ degcnt,
                        const int* __restrict__ partials,
                        int* __restrict__ rowptr, int* __restrict__ cursor,
                        float* __restrict__ dinv) {
    int i = blockIdx.x * blockDim.x + threadIdx.x;
    if (i < NN) {
        u64 dc = degcnt[i];
        int cnt = (int)(dc >> 40);
        int inc = tmp[i] + partials[i >> 8];
        rowptr[i + 1] = inc;
        cursor[i] = inc - cnt;
        if (i == 0) rowptr[0] = 0;
        float dg = (float)(dc & 0xFFFFFFFFFFull) * 5.9604644775390625e-08f;
        dinv[i] = (dg > 0.0f) ? rsqrtf(fmaxf(dg, 1e-12f)) : 0.0f;
    }
}

__global__ void k_bucket(const int* __restrict__ ei, const float* __restrict__ ew,
                         const float* __restrict__ dinv,
                         int* __restrict__ cursor, int2* __restrict__ eb) {
    int stride = gridDim.x * blockDim.x;
    for (int e = blockIdx.x * blockDim.x + threadIdx.x; e < NE; e += stride) {
        int s = ei[e], d = ei[NE + e];
        float nrm = dinv[s] * ew[e] * dinv[d];
        int pos = atomicAdd(&cursor[d], 1);
        eb[pos] = make_int2(s, __float_as_int(nrm));
    }
}

// ================= gathers =================
// one wave per dst node; lane l covers u32 slots 3l..3l+2 of the 192-u32 record.
// Agg layout == F layout (node-major), so writes are 3 consecutive dwords.

__global__ __launch_bounds__(256) void k_gather_xh(
    const int* __restrict__ rowptr, const int2* __restrict__ eb,
    const float* __restrict__ dinv, const uint32* __restrict__ F,
    uint32* __restrict__ AggU) {

    int l = threadIdx.x & 63;
    int d = __builtin_amdgcn_readfirstlane(blockIdx.x * 4 + (threadIdx.x >> 6));
    float dv = dinv[d];
    float s2 = dv * dv;

    const uint32* fp = F + 3 * l;
    const uint32* sp = fp + d * 192;
    uint32 u0 = sp[0], u1 = sp[1], u2 = sp[2];
    float a0 = s2 * blo(u0), a1 = s2 * bhi(u0);
    float a2 = s2 * blo(u1), a3 = s2 * bhi(u1);
    float a4 = s2 * blo(u2), a5 = s2 * bhi(u2);

    int e  = rowptr[d];
    int e1 = rowptr[d + 1];

    for (; e + 7 < e1; e += 8) {
        int2 p0 = eb[e],     p1 = eb[e + 1], p2 = eb[e + 2], p3 = eb[e + 3];
        int2 p4 = eb[e + 4], p5 = eb[e + 5], p6 = eb[e + 6], p7 = eb[e + 7];
        const uint32* q0 = fp + p0.x * 192;
        const uint32* q1 = fp + p1.x * 192;
        const uint32* q2 = fp + p2.x * 192;
        const uint32* q3 = fp + p3.x * 192;
        const uint32* q4 = fp + p4.x * 192;
        const uint32* q5 = fp + p5.x * 192;
        const uint32* q6 = fp + p6.x * 192;
        const uint32* q7 = fp + p7.x * 192;
        uint32 v00 = q0[0], v01 = q0[1], v02 = q0[2];
        uint32 v10 = q1[0], v11 = q1[1], v12 = q1[2];
        uint32 v20 = q2[0], v21 = q2[1], v22 = q2[2];
        uint32 v30 = q3[0], v31 = q3[1], v32 = q3[2];
        uint32 v40 = q4[0], v41 = q4[1], v42 = q4[2];
        uint32 v50 = q5[0], v51 = q5[1], v52 = q5[2];
        uint32 v60 = q6[0], v61 = q6[1], v62 = q6[2];
        uint32 v70 = q7[0], v71 = q7[1], v72 = q7[2];
        float n0 = __int_as_float(p0.y), n1 = __int_as_float(p1.y);
        float n2 = __int_as_float(p2.y), n3 = __int_as_float(p3.y);
        float n4 = __int_as_float(p4.y), n5 = __int_as_float(p5.y);
        float n6 = __int_as_float(p6.y), n7 = __int_as_float(p7.y);
        a0 = fmaf(n0, blo(v00), a0); a1 = fmaf(n0, bhi(v00), a1);
        a2 = fmaf(n0, blo(v01), a2); a3 = fmaf(n0, bhi(v01), a3);
        a4 = fmaf(n0, blo(v02), a4); a5 = fmaf(n0, bhi(v02), a5);
        a0 = fmaf(n1, blo(v10), a0); a1 = fmaf(n1, bhi(v10), a1);
        a2 = fmaf(n1, blo(v11), a2); a3 = fmaf(n1, bhi(v11), a3);
        a4 = fmaf(n1, blo(v12), a4); a5 = fmaf(n1, bhi(v12), a5);
        a0 = fmaf(n2, blo(v20), a0); a1 = fmaf(n2, bhi(v20), a1);
        a2 = fmaf(n2, blo(v21), a2); a3 = fmaf(n2, bhi(v21), a3);
        a4 = fmaf(n2, blo(v22), a4); a5 = fmaf(n2, bhi(v22), a5);
        a0 = fmaf(n3, blo(v30), a0); a1 = fmaf(n3, bhi(v30), a1);
        a2 = fmaf(n3, blo(v31), a2); a3 = fmaf(n3, bhi(v31), a3);
        a4 = fmaf(n3, blo(v32), a4); a5 = fmaf(n3, bhi(v32), a5);
        a0 = fmaf(n4, blo(v40), a0); a1 = fmaf(n4, bhi(v40), a1);
        a2 = fmaf(n4, blo(v41), a2); a3 = fmaf(n4, bhi(v41), a3);
        a4 = fmaf(n4, blo(v42), a4); a5 = fmaf(n4, bhi(v42), a5);
        a0 = fmaf(n5, blo(v50), a0); a1 = fmaf(n5, bhi(v50), a1);
        a2 = fmaf(n5, blo(v51), a2); a3 = fmaf(n5, bhi(v51), a3);
        a4 = fmaf(n5, blo(v52), a4); a5 = fmaf(n5, bhi(v52), a5);
        a0 = fmaf(n6, blo(v60), a0); a1 = fmaf(n6, bhi(v60), a1);
        a2 = fmaf(n6, blo(v61), a2); a3 = fmaf(n6, bhi(v61), a3);
        a4 = fmaf(n6, blo(v62), a4); a5 = fmaf(n6, bhi(v62), a5);
        a0 = fmaf(n7, blo(v70), a0); a1 = fmaf(n7, bhi(v70), a1);
        a2 = fmaf(n7, blo(v71), a2); a3 = fmaf(n7, bhi(v71), a3);
        a4 = fmaf(n7, blo(v72), a4); a5 = fmaf(n7, bhi(v72), a5);
    }
    for (; e + 3 < e1; e += 4) {
        int2 p0 = eb[e], p1 = eb[e + 1], p2 = eb[e + 2], p3 = eb[e + 3];
        const uint32* q0 = fp + p0.x * 192;
        const uint32* q1 = fp + p1.x * 192;
        const uint32* q2 = fp + p2.x * 192;
        const uint32* q3 = fp + p3.x * 192;
        uint32 v00 = q0[0], v01 = q0[1], v02 = q0[2];
        uint32 v10 = q1[0], v11 = q1[1], v12 = q1[2];
        uint32 v20 = q2[0], v21 = q2[1], v22 = q2[2];
        uint32 v30 = q3[0], v31 = q3[1], v32 = q3[2];
        float n0 = __int_as_float(p0.y), n1 = __int_as_float(p1.y);
        float n2 = __int_as_float(p2.y), n3 = __int_as_float(p3.y);
        a0 = fmaf(n0, blo(v00), a0); a1 = fmaf(n0, bhi(v00), a1);
        a2 = fmaf(n0, blo(v01), a2); a3 = fmaf(n0, bhi(v01), a3);
        a4 = fmaf(n0, blo(v02), a4); a5 = fmaf(n0, bhi(v02), a5);
        a0 = fmaf(n1, blo(v10), a0); a1 = fmaf(n1, bhi(v10), a1);
        a2 = fmaf(n1, blo(v11), a2); a3 = fmaf(n1, bhi(v11), a3);
        a4 = fmaf(n1, blo(v12), a4); a5 = fmaf(n1, bhi(v12), a5);
        a0 = fmaf(n2, blo(v20), a0); a1 = fmaf(n2, bhi(v20), a1);
        a2 = fmaf(n2, blo(v21), a2); a3 = fmaf(n2, bhi(v21), a3);
        a4 = fmaf(n2, blo(v22), a4); a5 = fmaf(n2, bhi(v22), a5);
        a0 = fmaf(n3, blo(v30), a0); a1 = fmaf(n3, bhi(v30), a1);
        a2 = fmaf(n3, blo(v31), a2); a3 = fmaf(n3, bhi(v31), a3);
        a4 = fmaf(n3, blo(v32), a4); a5 = fmaf(n3, bhi(v32), a5);
    }
    for (; e < e1; ++e) {
        int2 p0 = eb[e];
        const uint32* q0 = fp + p0.x * 192;
        uint32 v00 = q0[0], v01 = q0[1], v02 = q0[2];
        float n0 = __int_as_float(p0.y);
        a0 = fmaf(n0, blo(v00), a0); a1 = fmaf(n0, bhi(v00), a1);
        a2 = fmaf(n0, blo(v01), a2); a3 = fmaf(n0, bhi(v01), a3);
        a4 = fmaf(n0, blo(v02), a4); a5 = fmaf(n0, bhi(v02), a5);
    }

    uint32* op = AggU + d * 192 + 3 * l;
    op[0] = pk2(a0, a1);
    op[1] = pk2(a2, a3);
    op[2] = pk2(a4, a5);
}

// rh record R[n][128 u32] (bf16 slot = b*64 + ch), lane l covers u32 slots 2l,2l+1.
// writes Arh bf16 into Agg h-region (node-major): u32 slot d*192 + 64 + b*32 + cp
__global__ __launch_bounds__(256) void k_gather_rh(
    const int* __restrict__ rowptr, const int2* __restrict__ eb,
    const float* __restrict__ dinv, const uint32* __restrict__ R,
    uint32* __restrict__ AggU) {

    int l = threadIdx.x & 63;
    int d = __builtin_amdgcn_readfirstlane(blockIdx.x * 4 + (threadIdx.x >> 6));
    float dv = dinv[d];
    float s2 = dv * dv;

    const uint32* rp = R + 2 * l;
    uint2 sv = *(const uint2*)(rp + d * 128);
    float a0 = s2 * blo(sv.x), a1 = s2 * bhi(sv.x);
    float a2 = s2 * blo(sv.y), a3 = s2 * bhi(sv.y);

    int e  = rowptr[d];
    int e1 = rowptr[d + 1];

    for (; e + 7 < e1; e += 8) {
        int2 p0 = eb[e],     p1 = eb[e + 1], p2 = eb[e + 2], p3 = eb[e + 3];
        int2 p4 = eb[e + 4], p5 = eb[e + 5], p6 = eb[e + 6], p7 = eb[e + 7];
        uint2 v0 = *(const uint2*)(rp + p0.x * 128);
        uint2 v1 = *(const uint2*)(rp + p1.x * 128);
        uint2 v2 = *(const uint2*)(rp + p2.x * 128);
        uint2 v3 = *(const uint2*)(rp + p3.x * 128);
        uint2 v4 = *(const uint2*)(rp + p4.x * 128);
        uint2 v5 = *(const uint2*)(rp + p5.x * 128);
        uint2 v6 = *(const uint2*)(rp + p6.x * 128);
        uint2 v7 = *(const uint2*)(rp + p7.x * 128);
        float n0 = __int_as_float(p0.y), n1 = __int_as_float(p1.y);
        float n2 = __int_as_float(p2.y), n3 = __int_as_float(p3.y);
        float n4 = __int_as_float(p4.y), n5 = __int_as_float(p5.y);
        float n6 = __int_as_float(p6.y), n7 = __int_as_float(p7.y);
        a0 = fmaf(n0, blo(v0.x), a0); a1 = fmaf(n0, bhi(v0.x), a1);
        a2 = fmaf(n0, blo(v0.y), a2); a3 = fmaf(n0, bhi(v0.y), a3);
        a0 = fmaf(n1, blo(v1.x), a0); a1 = fmaf(n1, bhi(v1.x), a1);
        a2 = fmaf(n1, blo(v1.y), a2); a3 = fmaf(n1, bhi(v1.y), a3);
        a0 = fmaf(n2, blo(v2.x), a0); a1 = fmaf(n2, bhi(v2.x), a1);
        a2 = fmaf(n2, blo(v2.y), a2); a3 = fmaf(n2, bhi(v2.y), a3);
        a0 = fmaf(n3, blo(v3.x), a0); a1 = fmaf(n3, bhi(v3.x), a1);
        a2 = fmaf(n3, blo(v3.y), a2); a3 = fmaf(n3, bhi(v3.y), a3);
        a0 = fmaf(n4, blo(v4.x), a0); a1 = fmaf(n4, bhi(v4.x), a1);
        a2 = fmaf(n4, blo(v4.y), a2); a3 = fmaf(n4, bhi(v4.y), a3);
        a0 = fmaf(n5, blo(v5.x), a0); a1 = fmaf(n5, bhi(v5.x), a1);
        a2 = fmaf(n5, blo(v5.y), a2); a3 = fmaf(n5, bhi(v5.y), a3);
        a0 = fmaf(n6, blo(v6.x), a0); a1 = fmaf(n6, bhi(v6.x), a1);
        a2 = fmaf(n6, blo(v6.y), a2); a3 = fmaf(n6, bhi(v6.y), a3);
        a0 = fmaf(n7, blo(v7.x), a0); a1 = fmaf(n7, bhi(v7.x), a1);
        a2 = fmaf(n7, blo(v7.y), a2); a3 = fmaf(n7, bhi(v7.y), a3);
    }
    for (; e + 3 < e1; e += 4) {
        int2 p0 = eb[e], p1 = eb[e + 1], p2 = eb[e + 2], p3 = eb[e + 3];
        uint2 v0 = *(const uint2*)(rp + p0.x * 128);
        uint2 v1 = *(const uint2*)(rp + p1.x * 128);
        uint2 v2 = *(const uint2*)(rp + p2.x * 128);
        uint2 v3 = *(const uint2*)(rp + p3.x * 128);
        float n0 = __int_as_float(p0.y), n1 = __int_as_float(p1.y);
        float n2 = __int_as_float(p2.y), n3 = __int_as_float(p3.y);
        a0 = fmaf(n0, blo(v0.x), a0); a1 = fmaf(n0, bhi(v0.x), a1);
        a2 = fmaf(n0, blo(v0.y), a2); a3 = fmaf(n0, bhi(v0.y), a3);
        a0 = fmaf(n1, blo(v1.x), a0); a1 = fmaf(n1, bhi(v1.x), a1);
        a2 = fmaf(n1, blo(v1.y), a2); a3 = fmaf(n1, bhi(v1.y), a3);
        a0 = fmaf(n2, blo(v2.x), a0); a1 = fmaf(n2, bhi(v2.x), a1);
        a2 = fmaf(n2, blo(v2.y), a2); a3 = fmaf(n2, bhi(v2.y), a3);
        a0 = fmaf(n3, blo(v3.x), a0); a1 = fmaf(n3, bhi(v3.x), a1);
        a2 = fmaf(n3, blo(v3.y), a2); a3 = fmaf(n3, bhi(v3.y), a3);
    }
    for (; e < e1; ++e) {
        int2 p0 = eb[e];
        uint2 v0 = *(const uint2*)(rp + p0.x * 128);
        float n0 = __int_as_float(p0.y);
        a0 = fmaf(n0, blo(v0.x), a0); a1 = fmaf(n0, bhi(v0.x), a1);
        a2 = fmaf(n0, blo(v0.y), a2); a3 = fmaf(n0, bhi(v0.y), a3);
    }

    *(uint2*)&AggU[d * 192 + 64 + (l >> 4) * 32 + ((2 * l) & 31)] =
        make_uint2(pk2(a0, a1), pk2(a2, a3));
}

// ================= dense kernels (MFMA, weights in registers, grid-stride) =================

__global__ __launch_bounds__(256) void k_zr(
    const uint32* __restrict__ AggU, const float* __restrict__ h,
    const uint32* __restrict__ WB, const float* __restrict__ BS,
    ushort_t* __restrict__ Zb, ushort_t* __restrict__ R16) {

    int l  = threadIdx.x & 63;
    int wv = blockIdx.x * 4 + (threadIdx.x >> 6);    // 0..DWAVES-1
    int lr = l & 15, lg = l >> 4;

    const bf16x8* wz = (const bf16x8*)WB;
    const bf16x8* wr = (const bf16x8*)(WB + 3072);
    bf16x8 wzf[12], wrf[12];
    #pragma unroll
    for (int f = 0; f < 12; ++f) { wzf[f] = wz[f * 64 + l]; wrf[f] = wr[f * 64 + l]; }
    float bz[4], br[4];
    #pragma unroll
    for (int ct = 0; ct < 4; ++ct) {
        bz[ct] = BS[ct * 16 + lr];
        br[ct] = BS[64 + ct * 16 + lr];
    }

    for (int t = wv; t < NTILE; t += DWAVES) {
        int bb = t / TPB, nt = t - bb * TPB;
        const uint32* base = AggU + (nt * 16 + lr) * 192;
        bf16x8 af0 = *(const bf16x8*)(base + bb * 16 + lg * 4);
        bf16x8 af1 = *(const bf16x8*)(base + 64 + bb * 32 + lg * 4);
        bf16x8 af2 = *(const bf16x8*)(base + 64 + bb * 32 + 16 + lg * 4);

        f32x4 az[4], ar[4];
        #pragma unroll
        for (int c = 0; c < 4; ++c) { az[c] = (f32x4){0,0,0,0}; ar[c] = (f32x4){0,0,0,0}; }

        #pragma unroll
        for (int ct = 0; ct < 4; ++ct) {
            az[ct] = __builtin_amdgcn_mfma_f32_16x16x32_bf16(af0, wzf[0*4+ct], az[ct], 0,0,0);
            ar[ct] = __builtin_amdgcn_mfma_f32_16x16x32_bf16(af0, wrf[0*4+ct], ar[ct], 0,0,0);
            az[ct] = __builtin_amdgcn_mfma_f32_16x16x32_bf16(af1, wzf[1*4+ct], az[ct], 0,0,0);
            ar[ct] = __builtin_amdgcn_mfma_f32_16x16x32_bf16(af1, wrf[1*4+ct], ar[ct], 0,0,0);
            az[ct] = __builtin_amdgcn_mfma_f32_16x16x32_bf16(af2, wzf[2*4+ct], az[ct], 0,0,0);
            ar[ct] = __builtin_amdgcn_mfma_f32_16x16x32_bf16(af2, wrf[2*4+ct], ar[ct], 0,0,0);
        }

        int node0 = nt * 16;
        #pragma unroll
        for (int ct = 0; ct < 4; ++ct) {
            int ch = ct * 16 + lr;
            #pragma unroll
            for (int rr = 0; rr < 4; ++rr) {
                int node = node0 + lg * 4 + rr;
                int off  = (bb * NN + node) * 64 + ch;
                float zv = sigm(az[ct][rr] + bz[ct]);
                float rv = sigm(ar[ct][rr] + br[ct]);
                float hv = h[off];
                Zb[off] = b1(zv);
                R16[node * 256 + bb * 64 + ch] = b1(rv * hv);
            }
        }
    }
}

__global__ __launch_bounds__(256) void k_final(
    const uint32* __restrict__ AggU, const float* __restrict__ h,
    const uint32* __restrict__ WB, const float* __restrict__ BS,
    const ushort_t* __restrict__ Zb, float* __restrict__ out) {

    int l  = threadIdx.x & 63;
    int wv = blockIdx.x * 4 + (threadIdx.x >> 6);
    int lr = l & 15, lg = l >> 4;

    const bf16x8* wh = (const bf16x8*)(WB + 6144);
    bf16x8 whf[12];
    #pragma unroll
    for (int f = 0; f < 12; ++f) whf[f] = wh[f * 64 + l];
    float bs[4];
    #pragma unroll
    for (int ct = 0; ct < 4; ++ct) bs[ct] = BS[128 + ct * 16 + lr];

    for (int t = wv; t < NTILE; t += DWAVES) {
        int bb = t / TPB, nt = t - bb * TPB;
        const uint32* base = AggU + (nt * 16 + lr) * 192;
        bf16x8 af0 = *(const bf16x8*)(base + bb * 16 + lg * 4);
        bf16x8 af1 = *(const bf16x8*)(base + 64 + bb * 32 + lg * 4);
        bf16x8 af2 = *(const bf16x8*)(base + 64 + bb * 32 + 16 + lg * 4);

        f32x4 ac[4];
        #pragma unroll
        for (int c = 0; c < 4; ++c) ac[c] = (f32x4){0,0,0,0};

        #pragma unroll
        for (int ct = 0; ct < 4; ++ct) {
            ac[ct] = __builtin_amdgcn_mfma_f32_16x16x32_bf16(af0, whf[0*4+ct], ac[ct], 0,0,0);
            ac[ct] = __builtin_amdgcn_mfma_f32_16x16x32_bf16(af1, whf[1*4+ct], ac[ct], 0,0,0);
            ac[ct] = __builtin_amdgcn_mfma_f32_16x16x32_bf16(af2, whf[2*4+ct], ac[ct], 0,0,0);
        }

        int node0 = nt * 16;
        #pragma unroll
        for (int ct = 0; ct < 4; ++ct) {
            int ch = ct * 16 + lr;
            #pragma unroll
            for (int rr = 0; rr < 4; ++rr) {
                int node = node0 + lg * 4 + rr;
                int off  = (bb * NN + node) * 64 + ch;
                float hh = tanhf(ac[ct][rr] + bs[ct]);
                float zv = ub(Zb[off]);
                float hv = h[off];
                out[off] = (1.0f - zv) * hv + zv * hh;
            }
        }
    }
}

// ================= host launch =================

extern "C" void kernel_launch(void* const* d_in, const int* in_sizes, int n_in,
                              void* d_out, int out_size, void* d_ws, size_t ws_size,
                              hipStream_t stream) {
    const float* x   = (const float*)d_in[0];
    const float* h   = (const float*)d_in[1];
    const int*   ei  = (const int*)d_in[2];
    const float* ew  = (const float*)d_in[3];
    const float* Wuz = (const float*)d_in[4];
    const float* buz = (const float*)d_in[5];
    const float* Whz = (const float*)d_in[6];
    const float* bhz = (const float*)d_in[7];
    const float* Wur = (const float*)d_in[8];
    const float* bur = (const float*)d_in[9];
    const float* Whr = (const float*)d_in[10];
    const float* bhr = (const float*)d_in[11];
    const float* Wuh = (const float*)d_in[12];
    const float* buh = (const float*)d_in[13];
    const float* Whh = (const float*)d_in[14];
    const float* bhh = (const float*)d_in[15];
    float* out = (float*)d_out;

    // ws layout (4B words), total 27,516,864 words = 110.1 MB
    float*    w      = (float*)d_ws;
    u64*      degcnt = (u64*)w;                       // 102,400 (50,000 u64)
    float*    dinv   = w + 102400;                    // 51,200
    int*      rowptr = (int*)(w + 153600);            // 51,200
    int2*     eb     = (int2*)(w + 204800);           // 1,600,000
    uint32*   F      = (uint32*)(w + 1804800);        // 9,600,000 (dead after gather_xh)
    uint32*   R      = F;                             // aliases F: NN*128 = 6,400,000
    uint32*   AggU   = (uint32*)(w + 11404800);       // 9,600,000 (node-major, == F layout)
    ushort_t* Zb     = (ushort_t*)(w + 21004800);     // 6,400,000 words (12.8M bf16)
    uint32*   WB     = (uint32*)(w + 27404800);       // 9,216
    float*    BS     = (float*)(w + 27414016);        // 192
    int*      tmp    = (int*)(w + 27414208);          // 51,200
    int*      cursor = (int*)(w + 27465408);          // 51,200
    int*      parts  = (int*)(w + 27516608);          // 256

    k_prep<<<2048, 256, 0, stream>>>(x, h,
                                     Wuz, Whz, Wur, Whr, Wuh, Whh,
                                     buz, bhz, bur, bhr, buh, bhh,
                                     F, degcnt, WB, BS);
    k_degcnt<<<2048, 256, 0, stream>>>(ei, ew, degcnt);

    k_scan1<<<NBLK, 256, 0, stream>>>(degcnt, tmp, parts);
    k_scan2<<<1, 256, 0, stream>>>(parts);
    k_scan3<<<NBLK, 256, 0, stream>>>(tmp, degcnt, parts, rowptr, cursor, dinv);

    k_bucket<<<2048, 256, 0, stream>>>(ei, ew, dinv, cursor, eb);

    k_gather_xh<<<NN / 4, 256, 0, stream>>>(rowptr, eb, dinv, F, AggU);

    k_zr<<<DWAVES / 4, 256, 0, stream>>>(AggU, h, WB, BS, Zb, (ushort_t*)R);

    k_gather_rh<<<NN / 4, 256, 0, stream>>>(rowptr, eb, dinv, R, AggU);

    k_final<<<DWAVES / 4, 256, 0, stream>>>(AggU, h, WB, BS, Zb, out);
}

// Round 9
// 332.726 us; speedup vs baseline: 1.1472x; 1.0540x over previous
//
#include <hip/hip_runtime.h>
#include <math.h>

#define NN 50000
#define CIN 32
#define HD  64
#define NE  800000
#define NB  4
#define NBLK 196    // ceil(NN/256) scan blocks
#define NTILE 12500 // 200000 pairs / 16
#define TPB   3125  // tiles per batch (NN/16)
#define DWAVES 2048 // dense kernels: 512 blocks * 4 waves

typedef unsigned int uint32;
typedef unsigned short ushort_t;
typedef unsigned long long u64;
typedef __attribute__((ext_vector_type(8))) short bf16x8;
typedef __attribute__((ext_vector_type(4))) float f32x4;

// ---- bf16 pack/unpack helpers (RNE) ----
__device__ __forceinline__ uint32 pk2(float a, float b) {
    uint32 ua = __float_as_uint(a), ub = __float_as_uint(b);
    uint32 ra = (ua + 0x7FFFu + ((ua >> 16) & 1u)) >> 16;
    uint32 rb = (ub + 0x7FFFu + ((ub >> 16) & 1u)) >> 16;
    return ra | (rb << 16);
}
__device__ __forceinline__ float blo(uint32 v) { return __uint_as_float(v << 16); }
__device__ __forceinline__ float bhi(uint32 v) { return __uint_as_float(v & 0xFFFF0000u); }
__device__ __forceinline__ float sigm(float v) { return 1.0f / (1.0f + __expf(-v)); }

// ================= prepass (pure streaming, no atomics) =================
// F[n][192 u32] record: j in [0,64): x (b=j>>4, ch-pair j&15); j in [64,192): h
// (j'=j-64, b=j'>>5, ch-pair j'&31). Also: degcnt init + weight prepack.

__global__ void k_prep(const float4* __restrict__ x4, const float4* __restrict__ h4,
                       const float* __restrict__ Wuz, const float* __restrict__ Whz,
                       const float* __restrict__ Wur, const float* __restrict__ Whr,
                       const float* __restrict__ Wuh, const float* __restrict__ Whh,
                       const float* __restrict__ buz, const float* __restrict__ bhz,
                       const float* __restrict__ bur, const float* __restrict__ bhr,
                       const float* __restrict__ buh, const float* __restrict__ bhh,
                       uint2* __restrict__ F2, u64* __restrict__ degcnt,
                       uint32* __restrict__ WB, float* __restrict__ BS) {
    int stride = gridDim.x * blockDim.x;
    int tid = blockIdx.x * blockDim.x + threadIdx.x;

    if (tid < NN) degcnt[tid] = (1ull << 24);   // self-loop weight 1.0 fixed point

    if (tid < 9216) {   // weight frags (same (lane,elem)->k bijection as A packing)
        int g = tid / 3072, rem = tid - g * 3072;
        int kt = rem >> 10, r2 = rem & 1023;
        int ct = r2 >> 8, r3 = r2 & 255;
        int l = r3 >> 2, jp = r3 & 3;
        int k = kt * 32 + ((l >> 4) << 3) + 2 * jp;
        int ch = ct * 16 + (l & 15);
        const float* Wu = (g == 0) ? Wuz : (g == 1) ? Wur : Wuh;
        const float* Wh = (g == 0) ? Whz : (g == 1) ? Whr : Whh;
        float w0 = (k < 32) ? Wu[k * 64 + ch] : Wh[(k - 32) * 64 + ch];
        int k1 = k + 1;
        float w1 = (k1 < 32) ? Wu[k1 * 64 + ch] : Wh[(k1 - 32) * 64 + ch];
        WB[tid] = pk2(w0, w1);
    }
    if (tid < 192) {
        int g = tid >> 6, c = tid & 63;
        const float* bu = (g == 0) ? buz : (g == 1) ? bur : buh;
        const float* bh = (g == 0) ? bhz : (g == 1) ? bhr : bhh;
        BS[tid] = bu[c] + bh[c];
    }

    // x: NB*NN*8 float4 items
    for (int t = tid; t < NB * NN * (CIN / 4); t += stride) {
        int cq = t & 7; int rest = t >> 3;
        int b = rest / NN; int n = rest - b * NN;
        float4 v = x4[(b * NN + n) * 8 + cq];
        F2[n * 96 + b * 8 + cq] = make_uint2(pk2(v.x, v.y), pk2(v.z, v.w));
    }
    // h: NB*NN*16 float4 items
    for (int t = tid; t < NB * NN * (HD / 4); t += stride) {
        int cq = t & 15; int rest = t >> 4;
        int b = rest / NN; int n = rest - b * NN;
        float4 v = h4[(b * NN + n) * 16 + cq];
        F2[n * 96 + 32 + b * 16 + cq] = make_uint2(pk2(v.x, v.y), pk2(v.z, v.w));
    }
}

// one u64 atomic per edge: count in bits >=40, weight in 2^-24 fixed point low bits
__global__ void k_degcnt(const int* __restrict__ ei, const float* __restrict__ ew,
                         u64* __restrict__ degcnt) {
    int stride = gridDim.x * blockDim.x;
    for (int e = blockIdx.x * blockDim.x + threadIdx.x; e < NE; e += stride) {
        int d = ei[NE + e];
        u64 val = (1ull << 40) + (u64)(uint32)(ew[e] * 16777216.0f + 0.5f);
        atomicAdd(&degcnt[d], val);
    }
}

// ---- exclusive scan of counts -> rowptr, cursor; dinv ----

__global__ void k_scan1(const u64* __restrict__ degcnt, int* __restrict__ tmp,
                        int* __restrict__ partials) {
    __shared__ int lds[256];
    int i = blockIdx.x * 256 + threadIdx.x;
    int v = (i < NN) ? (int)(degcnt[i] >> 40) : 0;
    lds[threadIdx.x] = v;
    __syncthreads();
    for (int off = 1; off < 256; off <<= 1) {
        int t = (threadIdx.x >= off) ? lds[threadIdx.x - off] : 0;
        __syncthreads();
        lds[threadIdx.x] += t;
        __syncthreads();
    }
    if (i < NN) tmp[i] = lds[threadIdx.x];
    if (threadIdx.x == 255) partials[blockIdx.x] = lds[255];
}

__global__ void k_scan2(int* __restrict__ partials) {
    __shared__ int lds[256];
    int v = (threadIdx.x < NBLK) ? partials[threadIdx.x] : 0;
    lds[threadIdx.x] = v;
    __syncthreads();
    for (int off = 1; off < 256; off <<= 1) {
        int t = (threadIdx.x >= off) ? lds[threadIdx.x - off] : 0;
        __syncthreads();
        lds[threadIdx.x] += t;
        __syncthreads();
    }
    int ex = (threadIdx.x > 0) ? lds[threadIdx.x - 1] : 0;
    if (threadIdx.x < NBLK) partials[threadIdx.x] = ex;
}

__global__ void k_scan3(const int* __restrict__ tmp, const u64* __restrict__ degcnt,
                        const int* __restrict__ partials,
                        int* __restrict__ rowptr, int* __restrict__ cursor,
                        float* __restrict__ dinv) {
    int i = blockIdx.x * blockDim.x + threadIdx.x;
    if (i < NN) {
        u64 dc = degcnt[i];
        int cnt = (int)(dc >> 40);
        int inc = tmp[i] + partials[i >> 8];
        rowptr[i + 1] = inc;
        cursor[i] = inc - cnt;
        if (i == 0) rowptr[0] = 0;
        float dg = (float)(dc & 0xFFFFFFFFFFull) * 5.9604644775390625e-08f;
        dinv[i] = (dg > 0.0f) ? rsqrtf(fmaxf(dg, 1e-12f)) : 0.0f;
    }
}

__global__ void k_bucket(const int* __restrict__ ei, const float* __restrict__ ew,
                         const float* __restrict__ dinv,
                         int* __restrict__ cursor, int2* __restrict__ eb) {
    int stride = gridDim.x * blockDim.x;
    for (int e = blockIdx.x * blockDim.x + threadIdx.x; e < NE; e += stride) {
        int s = ei[e], d = ei[NE + e];
        float nrm = dinv[s] * ew[e] * dinv[d];
        int pos = atomicAdd(&cursor[d], 1);
        eb[pos] = make_int2(s, __float_as_int(nrm));
    }
}

// ================= gathers =================
// one wave per dst node; lane l covers u32 slots 3l..3l+2 of the 192-u32 record.
// Agg layout == F layout (node-major), so writes are 3 consecutive dwords.

__global__ __launch_bounds__(256) void k_gather_xh(
    const int* __restrict__ rowptr, const int2* __restrict__ eb,
    const float* __restrict__ dinv, const uint32* __restrict__ F,
    uint32* __restrict__ AggU) {

    int l = threadIdx.x & 63;
    int d = __builtin_amdgcn_readfirstlane(blockIdx.x * 4 + (threadIdx.x >> 6));
    float dv = dinv[d];
    float s2 = dv * dv;

    const uint32* fp = F + 3 * l;
    const uint32* sp = fp + d * 192;
    uint32 u0 = sp[0], u1 = sp[1], u2 = sp[2];
    float a0 = s2 * blo(u0), a1 = s2 * bhi(u0);
    float a2 = s2 * blo(u1), a3 = s2 * bhi(u1);
    float a4 = s2 * blo(u2), a5 = s2 * bhi(u2);

    int e  = rowptr[d];
    int e1 = rowptr[d + 1];

    for (; e + 7 < e1; e += 8) {
        int2 p0 = eb[e],     p1 = eb[e + 1], p2 = eb[e + 2], p3 = eb[e + 3];
        int2 p4 = eb[e + 4], p5 = eb[e + 5], p6 = eb[e + 6], p7 = eb[e + 7];
        const uint32* q0 = fp + p0.x * 192;
        const uint32* q1 = fp + p1.x * 192;
        const uint32* q2 = fp + p2.x * 192;
        const uint32* q3 = fp + p3.x * 192;
        const uint32* q4 = fp + p4.x * 192;
        const uint32* q5 = fp + p5.x * 192;
        const uint32* q6 = fp + p6.x * 192;
        const uint32* q7 = fp + p7.x * 192;
        uint32 v00 = q0[0], v01 = q0[1], v02 = q0[2];
        uint32 v10 = q1[0], v11 = q1[1], v12 = q1[2];
        uint32 v20 = q2[0], v21 = q2[1], v22 = q2[2];
        uint32 v30 = q3[0], v31 = q3[1], v32 = q3[2];
        uint32 v40 = q4[0], v41 = q4[1], v42 = q4[2];
        uint32 v50 = q5[0], v51 = q5[1], v52 = q5[2];
        uint32 v60 = q6[0], v61 = q6[1], v62 = q6[2];
        uint32 v70 = q7[0], v71 = q7[1], v72 = q7[2];
        float n0 = __int_as_float(p0.y), n1 = __int_as_float(p1.y);
        float n2 = __int_as_float(p2.y), n3 = __int_as_float(p3.y);
        float n4 = __int_as_float(p4.y), n5 = __int_as_float(p5.y);
        float n6 = __int_as_float(p6.y), n7 = __int_as_float(p7.y);
        a0 = fmaf(n0, blo(v00), a0); a1 = fmaf(n0, bhi(v00), a1);
        a2 = fmaf(n0, blo(v01), a2); a3 = fmaf(n0, bhi(v01), a3);
        a4 = fmaf(n0, blo(v02), a4); a5 = fmaf(n0, bhi(v02), a5);
        a0 = fmaf(n1, blo(v10), a0); a1 = fmaf(n1, bhi(v10), a1);
        a2 = fmaf(n1, blo(v11), a2); a3 = fmaf(n1, bhi(v11), a3);
        a4 = fmaf(n1, blo(v12), a4); a5 = fmaf(n1, bhi(v12), a5);
        a0 = fmaf(n2, blo(v20), a0); a1 = fmaf(n2, bhi(v20), a1);
        a2 = fmaf(n2, blo(v21), a2); a3 = fmaf(n2, bhi(v21), a3);
        a4 = fmaf(n2, blo(v22), a4); a5 = fmaf(n2, bhi(v22), a5);
        a0 = fmaf(n3, blo(v30), a0); a1 = fmaf(n3, bhi(v30), a1);
        a2 = fmaf(n3, blo(v31), a2); a3 = fmaf(n3, bhi(v31), a3);
        a4 = fmaf(n3, blo(v32), a4); a5 = fmaf(n3, bhi(v32), a5);
        a0 = fmaf(n4, blo(v40), a0); a1 = fmaf(n4, bhi(v40), a1);
        a2 = fmaf(n4, blo(v41), a2); a3 = fmaf(n4, bhi(v41), a3);
        a4 = fmaf(n4, blo(v42), a4); a5 = fmaf(n4, bhi(v42), a5);
        a0 = fmaf(n5, blo(v50), a0); a1 = fmaf(n5, bhi(v50), a1);
        a2 = fmaf(n5, blo(v51), a2); a3 = fmaf(n5, bhi(v51), a3);
        a4 = fmaf(n5, blo(v52), a4); a5 = fmaf(n5, bhi(v52), a5);
        a0 = fmaf(n6, blo(v60), a0); a1 = fmaf(n6, bhi(v60), a1);
        a2 = fmaf(n6, blo(v61), a2); a3 = fmaf(n6, bhi(v61), a3);
        a4 = fmaf(n6, blo(v62), a4); a5 = fmaf(n6, bhi(v62), a5);
        a0 = fmaf(n7, blo(v70), a0); a1 = fmaf(n7, bhi(v70), a1);
        a2 = fmaf(n7, blo(v71), a2); a3 = fmaf(n7, bhi(v71), a3);
        a4 = fmaf(n7, blo(v72), a4); a5 = fmaf(n7, bhi(v72), a5);
    }
    for (; e + 3 < e1; e += 4) {
        int2 p0 = eb[e], p1 = eb[e + 1], p2 = eb[e + 2], p3 = eb[e + 3];
        const uint32* q0 = fp + p0.x * 192;
        const uint32* q1 = fp + p1.x * 192;
        const uint32* q2 = fp + p2.x * 192;
        const uint32* q3 = fp + p3.x * 192;
        uint32 v00 = q0[0], v01 = q0[1], v02 = q0[2];
        uint32 v10 = q1[0], v11 = q1[1], v12 = q1[2];
        uint32 v20 = q2[0], v21 = q2[1], v22 = q2[2];
        uint32 v30 = q3[0], v31 = q3[1], v32 = q3[2];
        float n0 = __int_as_float(p0.y), n1 = __int_as_float(p1.y);
        float n2 = __int_as_float(p2.y), n3 = __int_as_float(p3.y);
        a0 = fmaf(n0, blo(v00), a0); a1 = fmaf(n0, bhi(v00), a1);
        a2 = fmaf(n0, blo(v01), a2); a3 = fmaf(n0, bhi(v01), a3);
        a4 = fmaf(n0, blo(v02), a4); a5 = fmaf(n0, bhi(v02), a5);
        a0 = fmaf(n1, blo(v10), a0); a1 = fmaf(n1, bhi(v10), a1);
        a2 = fmaf(n1, blo(v11), a2); a3 = fmaf(n1, bhi(v11), a3);
        a4 = fmaf(n1, blo(v12), a4); a5 = fmaf(n1, bhi(v12), a5);
        a0 = fmaf(n2, blo(v20), a0); a1 = fmaf(n2, bhi(v20), a1);
        a2 = fmaf(n2, blo(v21), a2); a3 = fmaf(n2, bhi(v21), a3);
        a4 = fmaf(n2, blo(v22), a4); a5 = fmaf(n2, bhi(v22), a5);
        a0 = fmaf(n3, blo(v30), a0); a1 = fmaf(n3, bhi(v30), a1);
        a2 = fmaf(n3, blo(v31), a2); a3 = fmaf(n3, bhi(v31), a3);
        a4 = fmaf(n3, blo(v32), a4); a5 = fmaf(n3, bhi(v32), a5);
    }
    for (; e < e1; ++e) {
        int2 p0 = eb[e];
        const uint32* q0 = fp + p0.x * 192;
        uint32 v00 = q0[0], v01 = q0[1], v02 = q0[2];
        float n0 = __int_as_float(p0.y);
        a0 = fmaf(n0, blo(v00), a0); a1 = fmaf(n0, bhi(v00), a1);
        a2 = fmaf(n0, blo(v01), a2); a3 = fmaf(n0, bhi(v01), a3);
        a4 = fmaf(n0, blo(v02), a4); a5 = fmaf(n0, bhi(v02), a5);
    }

    uint32* op = AggU + d * 192 + 3 * l;
    op[0] = pk2(a0, a1);
    op[1] = pk2(a2, a3);
    op[2] = pk2(a4, a5);
}

// rh record R[n][128 u32] (bf16 slot = b*64 + ch), lane l covers u32 slots 2l,2l+1.
// writes Arh bf16 into Agg h-region (node-major): u32 slot d*192 + 64 + b*32 + cp
__global__ __launch_bounds__(256) void k_gather_rh(
    const int* __restrict__ rowptr, const int2* __restrict__ eb,
    const float* __restrict__ dinv, const uint32* __restrict__ R,
    uint32* __restrict__ AggU) {

    int l = threadIdx.x & 63;
    int d = __builtin_amdgcn_readfirstlane(blockIdx.x * 4 + (threadIdx.x >> 6));
    float dv = dinv[d];
    float s2 = dv * dv;

    const uint32* rp = R + 2 * l;
    uint2 sv = *(const uint2*)(rp + d * 128);
    float a0 = s2 * blo(sv.x), a1 = s2 * bhi(sv.x);
    float a2 = s2 * blo(sv.y), a3 = s2 * bhi(sv.y);

    int e  = rowptr[d];
    int e1 = rowptr[d + 1];

    for (; e + 7 < e1; e += 8) {
        int2 p0 = eb[e],     p1 = eb[e + 1], p2 = eb[e + 2], p3 = eb[e + 3];
        int2 p4 = eb[e + 4], p5 = eb[e + 5], p6 = eb[e + 6], p7 = eb[e + 7];
        uint2 v0 = *(const uint2*)(rp + p0.x * 128);
        uint2 v1 = *(const uint2*)(rp + p1.x * 128);
        uint2 v2 = *(const uint2*)(rp + p2.x * 128);
        uint2 v3 = *(const uint2*)(rp + p3.x * 128);
        uint2 v4 = *(const uint2*)(rp + p4.x * 128);
        uint2 v5 = *(const uint2*)(rp + p5.x * 128);
        uint2 v6 = *(const uint2*)(rp + p6.x * 128);
        uint2 v7 = *(const uint2*)(rp + p7.x * 128);
        float n0 = __int_as_float(p0.y), n1 = __int_as_float(p1.y);
        float n2 = __int_as_float(p2.y), n3 = __int_as_float(p3.y);
        float n4 = __int_as_float(p4.y), n5 = __int_as_float(p5.y);
        float n6 = __int_as_float(p6.y), n7 = __int_as_float(p7.y);
        a0 = fmaf(n0, blo(v0.x), a0); a1 = fmaf(n0, bhi(v0.x), a1);
        a2 = fmaf(n0, blo(v0.y), a2); a3 = fmaf(n0, bhi(v0.y), a3);
        a0 = fmaf(n1, blo(v1.x), a0); a1 = fmaf(n1, bhi(v1.x), a1);
        a2 = fmaf(n1, blo(v1.y), a2); a3 = fmaf(n1, bhi(v1.y), a3);
        a0 = fmaf(n2, blo(v2.x), a0); a1 = fmaf(n2, bhi(v2.x), a1);
        a2 = fmaf(n2, blo(v2.y), a2); a3 = fmaf(n2, bhi(v2.y), a3);
        a0 = fmaf(n3, blo(v3.x), a0); a1 = fmaf(n3, bhi(v3.x), a1);
        a2 = fmaf(n3, blo(v3.y), a2); a3 = fmaf(n3, bhi(v3.y), a3);
        a0 = fmaf(n4, blo(v4.x), a0); a1 = fmaf(n4, bhi(v4.x), a1);
        a2 = fmaf(n4, blo(v4.y), a2); a3 = fmaf(n4, bhi(v4.y), a3);
        a0 = fmaf(n5, blo(v5.x), a0); a1 = fmaf(n5, bhi(v5.x), a1);
        a2 = fmaf(n5, blo(v5.y), a2); a3 = fmaf(n5, bhi(v5.y), a3);
        a0 = fmaf(n6, blo(v6.x), a0); a1 = fmaf(n6, bhi(v6.x), a1);
        a2 = fmaf(n6, blo(v6.y), a2); a3 = fmaf(n6, bhi(v6.y), a3);
        a0 = fmaf(n7, blo(v7.x), a0); a1 = fmaf(n7, bhi(v7.x), a1);
        a2 = fmaf(n7, blo(v7.y), a2); a3 = fmaf(n7, bhi(v7.y), a3);
    }
    for (; e + 3 < e1; e += 4) {
        int2 p0 = eb[e], p1 = eb[e + 1], p2 = eb[e + 2], p3 = eb[e + 3];
        uint2 v0 = *(const uint2*)(rp + p0.x * 128);
        uint2 v1 = *(const uint2*)(rp + p1.x * 128);
        uint2 v2 = *(const uint2*)(rp + p2.x * 128);
        uint2 v3 = *(const uint2*)(rp + p3.x * 128);
        float n0 = __int_as_float(p0.y), n1 = __int_as_float(p1.y);
        float n2 = __int_as_float(p2.y), n3 = __int_as_float(p3.y);
        a0 = fmaf(n0, blo(v0.x), a0); a1 = fmaf(n0, bhi(v0.x), a1);
        a2 = fmaf(n0, blo(v0.y), a2); a3 = fmaf(n0, bhi(v0.y), a3);
        a0 = fmaf(n1, blo(v1.x), a0); a1 = fmaf(n1, bhi(v1.x), a1);
        a2 = fmaf(n1, blo(v1.y), a2); a3 = fmaf(n1, bhi(v1.y), a3);
        a0 = fmaf(n2, blo(v2.x), a0); a1 = fmaf(n2, bhi(v2.x), a1);
        a2 = fmaf(n2, blo(v2.y), a2); a3 = fmaf(n2, bhi(v2.y), a3);
        a0 = fmaf(n3, blo(v3.x), a0); a1 = fmaf(n3, bhi(v3.x), a1);
        a2 = fmaf(n3, blo(v3.y), a2); a3 = fmaf(n3, bhi(v3.y), a3);
    }
    for (; e < e1; ++e) {
        int2 p0 = eb[e];
        uint2 v0 = *(const uint2*)(rp + p0.x * 128);
        float n0 = __int_as_float(p0.y);
        a0 = fmaf(n0, blo(v0.x), a0); a1 = fmaf(n0, bhi(v0.x), a1);
        a2 = fmaf(n0, blo(v0.y), a2); a3 = fmaf(n0, bhi(v0.y), a3);
    }

    *(uint2*)&AggU[d * 192 + 64 + (l >> 4) * 32 + ((2 * l) & 31)] =
        make_uint2(pk2(a0, a1), pk2(a2, a3));
}

// ================= dense kernels (MFMA, weights in registers, grid-stride) =================
// h is read as bf16 from the F record (F stays alive; R is a separate buffer).

__global__ __launch_bounds__(256) void k_zr(
    const uint32* __restrict__ AggU, const uint32* __restrict__ F,
    const uint32* __restrict__ WB, const float* __restrict__ BS,
    uint2* __restrict__ Zb2, ushort_t* __restrict__ R16) {

    int l  = threadIdx.x & 63;
    int wv = blockIdx.x * 4 + (threadIdx.x >> 6);    // 0..DWAVES-1
    int lr = l & 15, lg = l >> 4;

    const bf16x8* wz = (const bf16x8*)WB;
    const bf16x8* wr = (const bf16x8*)(WB + 3072);
    bf16x8 wzf[12], wrf[12];
    #pragma unroll
    for (int f = 0; f < 12; ++f) { wzf[f] = wz[f * 64 + l]; wrf[f] = wr[f * 64 + l]; }
    float bz[4], br[4];
    #pragma unroll
    for (int ct = 0; ct < 4; ++ct) {
        bz[ct] = BS[ct * 16 + lr];
        br[ct] = BS[64 + ct * 16 + lr];
    }

    for (int t = wv; t < NTILE; t += DWAVES) {
        int bb = t / TPB, nt = t - bb * TPB;
        const uint32* base = AggU + (nt * 16 + lr) * 192;
        bf16x8 af0 = *(const bf16x8*)(base + bb * 16 + lg * 4);
        bf16x8 af1 = *(const bf16x8*)(base + 64 + bb * 32 + lg * 4);
        bf16x8 af2 = *(const bf16x8*)(base + 64 + bb * 32 + 16 + lg * 4);

        f32x4 az[4], ar[4];
        #pragma unroll
        for (int c = 0; c < 4; ++c) { az[c] = (f32x4){0,0,0,0}; ar[c] = (f32x4){0,0,0,0}; }

        #pragma unroll
        for (int ct = 0; ct < 4; ++ct) {
            az[ct] = __builtin_amdgcn_mfma_f32_16x16x32_bf16(af0, wzf[0*4+ct], az[ct], 0,0,0);
            ar[ct] = __builtin_amdgcn_mfma_f32_16x16x32_bf16(af0, wrf[0*4+ct], ar[ct], 0,0,0);
            az[ct] = __builtin_amdgcn_mfma_f32_16x16x32_bf16(af1, wzf[1*4+ct], az[ct], 0,0,0);
            ar[ct] = __builtin_amdgcn_mfma_f32_16x16x32_bf16(af1, wrf[1*4+ct], ar[ct], 0,0,0);
            az[ct] = __builtin_amdgcn_mfma_f32_16x16x32_bf16(af2, wzf[2*4+ct], az[ct], 0,0,0);
            ar[ct] = __builtin_amdgcn_mfma_f32_16x16x32_bf16(af2, wrf[2*4+ct], ar[ct], 0,0,0);
        }

        int node0 = nt * 16;
        #pragma unroll
        for (int ct = 0; ct < 4; ++ct) {
            int ch = ct * 16 + lr;
            uint32 z01, z23;
            #pragma unroll
            for (int rr = 0; rr < 4; ++rr) {
                int node = node0 + lg * 4 + rr;
                float zv = sigm(az[ct][rr] + bz[ct]);
                float rv = sigm(ar[ct][rr] + br[ct]);
                uint32 hu = F[node * 192 + 64 + bb * 32 + ct * 8 + (lr >> 1)];
                float hv = (lr & 1) ? bhi(hu) : blo(hu);
                uint32 zb = (__float_as_uint(zv) + 0x7FFFu + ((__float_as_uint(zv) >> 16) & 1u)) >> 16;
                if (rr == 0) z01 = zb;
                else if (rr == 1) z01 |= zb << 16;
                else if (rr == 2) z23 = zb;
                else z23 |= zb << 16;
                float rh = rv * hv;
                uint32 ru = __float_as_uint(rh);
                R16[node * 256 + bb * 64 + ch] =
                    (ushort_t)((ru + 0x7FFFu + ((ru >> 16) & 1u)) >> 16);
            }
            Zb2[(t * 4 + ct) * 64 + l] = make_uint2(z01, z23);
        }
    }
}

__global__ __launch_bounds__(256) void k_final(
    const uint32* __restrict__ AggU, const uint32* __restrict__ F,
    const uint32* __restrict__ WB, const float* __restrict__ BS,
    const uint2* __restrict__ Zb2, float* __restrict__ out) {

    int l  = threadIdx.x & 63;
    int wv = blockIdx.x * 4 + (threadIdx.x >> 6);
    int lr = l & 15, lg = l >> 4;

    const bf16x8* wh = (const bf16x8*)(WB + 6144);
    bf16x8 whf[12];
    #pragma unroll
    for (int f = 0; f < 12; ++f) whf[f] = wh[f * 64 + l];
    float bs[4];
    #pragma unroll
    for (int ct = 0; ct < 4; ++ct) bs[ct] = BS[128 + ct * 16 + lr];

    for (int t = wv; t < NTILE; t += DWAVES) {
        int bb = t / TPB, nt = t - bb * TPB;
        const uint32* base = AggU + (nt * 16 + lr) * 192;
        bf16x8 af0 = *(const bf16x8*)(base + bb * 16 + lg * 4);
        bf16x8 af1 = *(const bf16x8*)(base + 64 + bb * 32 + lg * 4);
        bf16x8 af2 = *(const bf16x8*)(base + 64 + bb * 32 + 16 + lg * 4);

        f32x4 ac[4];
        #pragma unroll
        for (int c = 0; c < 4; ++c) ac[c] = (f32x4){0,0,0,0};

        #pragma unroll
        for (int ct = 0; ct < 4; ++ct) {
            ac[ct] = __builtin_amdgcn_mfma_f32_16x16x32_bf16(af0, whf[0*4+ct], ac[ct], 0,0,0);
            ac[ct] = __builtin_amdgcn_mfma_f32_16x16x32_bf16(af1, whf[1*4+ct], ac[ct], 0,0,0);
            ac[ct] = __builtin_amdgcn_mfma_f32_16x16x32_bf16(af2, whf[2*4+ct], ac[ct], 0,0,0);
        }

        int node0 = nt * 16;
        #pragma unroll
        for (int ct = 0; ct < 4; ++ct) {
            int ch = ct * 16 + lr;
            uint2 zv2 = Zb2[(t * 4 + ct) * 64 + l];
            #pragma unroll
            for (int rr = 0; rr < 4; ++rr) {
                int node = node0 + lg * 4 + rr;
                int off  = (bb * NN + node) * 64 + ch;
                float hh = tanhf(ac[ct][rr] + bs[ct]);
                float zv = (rr == 0) ? blo(zv2.x) : (rr == 1) ? bhi(zv2.x)
                         : (rr == 2) ? blo(zv2.y) : bhi(zv2.y);
                uint32 hu = F[node * 192 + 64 + bb * 32 + ct * 8 + (lr >> 1)];
                float hv = (lr & 1) ? bhi(hu) : blo(hu);
                out[off] = (1.0f - zv) * hv + zv * hh;
            }
        }
    }
}

// ================= host launch =================

extern "C" void kernel_launch(void* const* d_in, const int* in_sizes, int n_in,
                              void* d_out, int out_size, void* d_ws, size_t ws_size,
                              hipStream_t stream) {
    const float* x   = (const float*)d_in[0];
    const float* h   = (const float*)d_in[1];
    const int*   ei  = (const int*)d_in[2];
    const float* ew  = (const float*)d_in[3];
    const float* Wuz = (const float*)d_in[4];
    const float* buz = (const float*)d_in[5];
    const float* Whz = (const float*)d_in[6];
    const float* bhz = (const float*)d_in[7];
    const float* Wur = (const float*)d_in[8];
    const float* bur = (const float*)d_in[9];
    const float* Whr = (const float*)d_in[10];
    const float* bhr = (const float*)d_in[11];
    const float* Wuh = (const float*)d_in[12];
    const float* buh = (const float*)d_in[13];
    const float* Whh = (const float*)d_in[14];
    const float* bhh = (const float*)d_in[15];
    float* out = (float*)d_out;

    // ws layout (4B words), total 33,711,808 words = 134.85 MB
    // Zb region [0 .. 6.4M) also hosts degcnt/tmp/cursor/parts (all dead before
    // k_zr writes Zb).
    float*    w      = (float*)d_ws;
    u64*      degcnt = (u64*)w;                       // 102,400 (dead after scan3)
    int*      tmp    = (int*)(w + 102400);            // 51,200 (dead after scan3)
    int*      cursor = (int*)(w + 153600);            // 51,200 (dead after bucket)
    int*      parts  = (int*)(w + 204800);            // 256    (dead after scan3)
    uint2*    Zb2    = (uint2*)w;                     // 6,400,000 words (k_zr onward)
    float*    dinv   = w + 6400000;                   // 51,200
    int*      rowptr = (int*)(w + 6451200);           // 51,200
    int2*     eb     = (int2*)(w + 6502400);          // 1,600,000
    uint32*   F      = (uint32*)(w + 8102400);        // 9,600,000 (alive to the end)
    uint32*   AggU   = (uint32*)(w + 17702400);       // 9,600,000
    uint32*   R      = (uint32*)(w + 27302400);       // 6,400,000
    uint32*   WB     = (uint32*)(w + 33702400);       // 9,216
    float*    BS     = (float*)(w + 33711616);        // 192

    k_prep<<<2048, 256, 0, stream>>>((const float4*)x, (const float4*)h,
                                     Wuz, Whz, Wur, Whr, Wuh, Whh,
                                     buz, bhz, bur, bhr, buh, bhh,
                                     (uint2*)F, degcnt, WB, BS);
    k_degcnt<<<2048, 256, 0, stream>>>(ei, ew, degcnt);

    k_scan1<<<NBLK, 256, 0, stream>>>(degcnt, tmp, parts);
    k_scan2<<<1, 256, 0, stream>>>(parts);
    k_scan3<<<NBLK, 256, 0, stream>>>(tmp, degcnt, parts, rowptr, cursor, dinv);

    k_bucket<<<2048, 256, 0, stream>>>(ei, ew, dinv, cursor, eb);

    k_gather_xh<<<NN / 4, 256, 0, stream>>>(rowptr, eb, dinv, F, AggU);

    k_zr<<<DWAVES / 4, 256, 0, stream>>>(AggU, F, WB, BS, Zb2, (ushort_t*)R);

    k_gather_rh<<<NN / 4, 256, 0, stream>>>(rowptr, eb, dinv, R, AggU);

    k_final<<<DWAVES / 4, 256, 0, stream>>>(AggU, F, WB, BS, Zb2, out);
}

// Round 10
// 324.207 us; speedup vs baseline: 1.1774x; 1.0263x over previous
//
#include <hip/hip_runtime.h>
#include <math.h>

#define NN 50000
#define CIN 32
#define HD  64
#define NE  800000
#define NB  4
#define NBLK 196    // ceil(NN/256) scan blocks
#define NTILE 12500 // 200000 pairs / 16
#define TPB   3125  // tiles per batch (NN/16)
#define DWAVES 4096 // dense kernels: 1024 blocks * 4 waves

typedef unsigned int uint32;
typedef unsigned short ushort_t;
typedef unsigned long long u64;
typedef __attribute__((ext_vector_type(8))) short bf16x8;
typedef __attribute__((ext_vector_type(4))) float f32x4;

// ---- bf16 pack/unpack helpers (RNE) ----
__device__ __forceinline__ uint32 pk2(float a, float b) {
    uint32 ua = __float_as_uint(a), ub = __float_as_uint(b);
    uint32 ra = (ua + 0x7FFFu + ((ua >> 16) & 1u)) >> 16;
    uint32 rb = (ub + 0x7FFFu + ((ub >> 16) & 1u)) >> 16;
    return ra | (rb << 16);
}
__device__ __forceinline__ float blo(uint32 v) { return __uint_as_float(v << 16); }
__device__ __forceinline__ float bhi(uint32 v) { return __uint_as_float(v & 0xFFFF0000u); }
__device__ __forceinline__ float sigm(float v) { return 1.0f / (1.0f + __expf(-v)); }

// ================= prepass (pure streaming, no atomics) =================
// F[n][192 u32] record: j in [0,64): x (b=j>>4, ch-pair j&15); j in [64,192): h
// (j'=j-64, b=j'>>5, ch-pair j'&31). Also: degcnt init + weight prepack.

__global__ void k_prep(const float4* __restrict__ x4, const float4* __restrict__ h4,
                       const float* __restrict__ Wuz, const float* __restrict__ Whz,
                       const float* __restrict__ Wur, const float* __restrict__ Whr,
                       const float* __restrict__ Wuh, const float* __restrict__ Whh,
                       const float* __restrict__ buz, const float* __restrict__ bhz,
                       const float* __restrict__ bur, const float* __restrict__ bhr,
                       const float* __restrict__ buh, const float* __restrict__ bhh,
                       uint2* __restrict__ F2, u64* __restrict__ degcnt,
                       uint32* __restrict__ WB, float* __restrict__ BS) {
    int stride = gridDim.x * blockDim.x;
    int tid = blockIdx.x * blockDim.x + threadIdx.x;

    if (tid < NN) degcnt[tid] = (1ull << 24);   // self-loop weight 1.0 fixed point

    if (tid < 9216) {   // weight frags (same (lane,elem)->k bijection as A packing)
        int g = tid / 3072, rem = tid - g * 3072;
        int kt = rem >> 10, r2 = rem & 1023;
        int ct = r2 >> 8, r3 = r2 & 255;
        int l = r3 >> 2, jp = r3 & 3;
        int k = kt * 32 + ((l >> 4) << 3) + 2 * jp;
        int ch = ct * 16 + (l & 15);
        const float* Wu = (g == 0) ? Wuz : (g == 1) ? Wur : Wuh;
        const float* Wh = (g == 0) ? Whz : (g == 1) ? Whr : Whh;
        float w0 = (k < 32) ? Wu[k * 64 + ch] : Wh[(k - 32) * 64 + ch];
        int k1 = k + 1;
        float w1 = (k1 < 32) ? Wu[k1 * 64 + ch] : Wh[(k1 - 32) * 64 + ch];
        WB[tid] = pk2(w0, w1);
    }
    if (tid < 192) {
        int g = tid >> 6, c = tid & 63;
        const float* bu = (g == 0) ? buz : (g == 1) ? bur : buh;
        const float* bh = (g == 0) ? bhz : (g == 1) ? bhr : bhh;
        BS[tid] = bu[c] + bh[c];
    }

    // x: NB*NN*8 float4 items
    for (int t = tid; t < NB * NN * (CIN / 4); t += stride) {
        int cq = t & 7; int rest = t >> 3;
        int b = rest / NN; int n = rest - b * NN;
        float4 v = x4[(b * NN + n) * 8 + cq];
        F2[n * 96 + b * 8 + cq] = make_uint2(pk2(v.x, v.y), pk2(v.z, v.w));
    }
    // h: NB*NN*16 float4 items
    for (int t = tid; t < NB * NN * (HD / 4); t += stride) {
        int cq = t & 15; int rest = t >> 4;
        int b = rest / NN; int n = rest - b * NN;
        float4 v = h4[(b * NN + n) * 16 + cq];
        F2[n * 96 + 32 + b * 16 + cq] = make_uint2(pk2(v.x, v.y), pk2(v.z, v.w));
    }
}

// one u64 atomic per edge: count in bits >=40, weight in 2^-24 fixed point low bits
__global__ void k_degcnt(const int* __restrict__ ei, const float* __restrict__ ew,
                         u64* __restrict__ degcnt) {
    int stride = gridDim.x * blockDim.x;
    for (int e = blockIdx.x * blockDim.x + threadIdx.x; e < NE; e += stride) {
        int d = ei[NE + e];
        u64 val = (1ull << 40) + (u64)(uint32)(ew[e] * 16777216.0f + 0.5f);
        atomicAdd(&degcnt[d], val);
    }
}

// ---- scan of counts -> rowptr, cursor; dinv (scan2 folded into scan3) ----

__global__ void k_scan1(const u64* __restrict__ degcnt, int* __restrict__ tmp,
                        int* __restrict__ partials) {
    __shared__ int lds[256];
    int i = blockIdx.x * 256 + threadIdx.x;
    int v = (i < NN) ? (int)(degcnt[i] >> 40) : 0;
    lds[threadIdx.x] = v;
    __syncthreads();
    for (int off = 1; off < 256; off <<= 1) {
        int t = (threadIdx.x >= off) ? lds[threadIdx.x - off] : 0;
        __syncthreads();
        lds[threadIdx.x] += t;
        __syncthreads();
    }
    if (i < NN) tmp[i] = lds[threadIdx.x];
    if (threadIdx.x == 255) partials[blockIdx.x] = lds[255];
}

// each block locally exclusive-scans partials[NBLK] in LDS (no global mutation)
__global__ void k_scan3(const int* __restrict__ tmp, const u64* __restrict__ degcnt,
                        const int* __restrict__ partials,
                        int* __restrict__ rowptr, int* __restrict__ cursor,
                        float* __restrict__ dinv) {
    __shared__ int lds[256];
    int v = (threadIdx.x < NBLK) ? partials[threadIdx.x] : 0;
    lds[threadIdx.x] = v;
    __syncthreads();
    for (int off = 1; off < 256; off <<= 1) {
        int t = (threadIdx.x >= off) ? lds[threadIdx.x - off] : 0;
        __syncthreads();
        lds[threadIdx.x] += t;
        __syncthreads();
    }
    // lds now holds inclusive scan; exclusive = lds[j-1]
    int i = blockIdx.x * blockDim.x + threadIdx.x;
    if (i < NN) {
        int blk = i >> 8;
        int ex = (blk > 0) ? lds[blk - 1] : 0;
        u64 dc = degcnt[i];
        int cnt = (int)(dc >> 40);
        int inc = tmp[i] + ex;
        rowptr[i + 1] = inc;
        cursor[i] = inc - cnt;
        if (i == 0) rowptr[0] = 0;
        float dg = (float)(dc & 0xFFFFFFFFFFull) * 5.9604644775390625e-08f;
        dinv[i] = (dg > 0.0f) ? rsqrtf(fmaxf(dg, 1e-12f)) : 0.0f;
    }
}

__global__ void k_bucket(const int* __restrict__ ei, const float* __restrict__ ew,
                         const float* __restrict__ dinv,
                         int* __restrict__ cursor, int2* __restrict__ eb) {
    int stride = gridDim.x * blockDim.x;
    for (int e = blockIdx.x * blockDim.x + threadIdx.x; e < NE; e += stride) {
        int s = ei[e], d = ei[NE + e];
        float nrm = dinv[s] * ew[e] * dinv[d];
        int pos = atomicAdd(&cursor[d], 1);
        eb[pos] = make_int2(s, __float_as_int(nrm));
    }
}

// ================= gathers =================
// one wave per dst node; lane l covers u32 slots 3l..3l+2 of the 192-u32 record.
// Agg layout == F layout (node-major), so writes are 3 consecutive dwords.

__global__ __launch_bounds__(256) void k_gather_xh(
    const int* __restrict__ rowptr, const int2* __restrict__ eb,
    const float* __restrict__ dinv, const uint32* __restrict__ F,
    uint32* __restrict__ AggU) {

    int l = threadIdx.x & 63;
    int d = __builtin_amdgcn_readfirstlane(blockIdx.x * 4 + (threadIdx.x >> 6));
    float dv = dinv[d];
    float s2 = dv * dv;

    const uint32* fp = F + 3 * l;
    const uint32* sp = fp + d * 192;
    uint32 u0 = sp[0], u1 = sp[1], u2 = sp[2];
    float a0 = s2 * blo(u0), a1 = s2 * bhi(u0);
    float a2 = s2 * blo(u1), a3 = s2 * bhi(u1);
    float a4 = s2 * blo(u2), a5 = s2 * bhi(u2);

    int e  = rowptr[d];
    int e1 = rowptr[d + 1];

    for (; e + 7 < e1; e += 8) {
        int2 p0 = eb[e],     p1 = eb[e + 1], p2 = eb[e + 2], p3 = eb[e + 3];
        int2 p4 = eb[e + 4], p5 = eb[e + 5], p6 = eb[e + 6], p7 = eb[e + 7];
        const uint32* q0 = fp + p0.x * 192;
        const uint32* q1 = fp + p1.x * 192;
        const uint32* q2 = fp + p2.x * 192;
        const uint32* q3 = fp + p3.x * 192;
        const uint32* q4 = fp + p4.x * 192;
        const uint32* q5 = fp + p5.x * 192;
        const uint32* q6 = fp + p6.x * 192;
        const uint32* q7 = fp + p7.x * 192;
        uint32 v00 = q0[0], v01 = q0[1], v02 = q0[2];
        uint32 v10 = q1[0], v11 = q1[1], v12 = q1[2];
        uint32 v20 = q2[0], v21 = q2[1], v22 = q2[2];
        uint32 v30 = q3[0], v31 = q3[1], v32 = q3[2];
        uint32 v40 = q4[0], v41 = q4[1], v42 = q4[2];
        uint32 v50 = q5[0], v51 = q5[1], v52 = q5[2];
        uint32 v60 = q6[0], v61 = q6[1], v62 = q6[2];
        uint32 v70 = q7[0], v71 = q7[1], v72 = q7[2];
        float n0 = __int_as_float(p0.y), n1 = __int_as_float(p1.y);
        float n2 = __int_as_float(p2.y), n3 = __int_as_float(p3.y);
        float n4 = __int_as_float(p4.y), n5 = __int_as_float(p5.y);
        float n6 = __int_as_float(p6.y), n7 = __int_as_float(p7.y);
        a0 = fmaf(n0, blo(v00), a0); a1 = fmaf(n0, bhi(v00), a1);
        a2 = fmaf(n0, blo(v01), a2); a3 = fmaf(n0, bhi(v01), a3);
        a4 = fmaf(n0, blo(v02), a4); a5 = fmaf(n0, bhi(v02), a5);
        a0 = fmaf(n1, blo(v10), a0); a1 = fmaf(n1, bhi(v10), a1);
        a2 = fmaf(n1, blo(v11), a2); a3 = fmaf(n1, bhi(v11), a3);
        a4 = fmaf(n1, blo(v12), a4); a5 = fmaf(n1, bhi(v12), a5);
        a0 = fmaf(n2, blo(v20), a0); a1 = fmaf(n2, bhi(v20), a1);
        a2 = fmaf(n2, blo(v21), a2); a3 = fmaf(n2, bhi(v21), a3);
        a4 = fmaf(n2, blo(v22), a4); a5 = fmaf(n2, bhi(v22), a5);
        a0 = fmaf(n3, blo(v30), a0); a1 = fmaf(n3, bhi(v30), a1);
        a2 = fmaf(n3, blo(v31), a2); a3 = fmaf(n3, bhi(v31), a3);
        a4 = fmaf(n3, blo(v32), a4); a5 = fmaf(n3, bhi(v32), a5);
        a0 = fmaf(n4, blo(v40), a0); a1 = fmaf(n4, bhi(v40), a1);
        a2 = fmaf(n4, blo(v41), a2); a3 = fmaf(n4, bhi(v41), a3);
        a4 = fmaf(n4, blo(v42), a4); a5 = fmaf(n4, bhi(v42), a5);
        a0 = fmaf(n5, blo(v50), a0); a1 = fmaf(n5, bhi(v50), a1);
        a2 = fmaf(n5, blo(v51), a2); a3 = fmaf(n5, bhi(v51), a3);
        a4 = fmaf(n5, blo(v52), a4); a5 = fmaf(n5, bhi(v52), a5);
        a0 = fmaf(n6, blo(v60), a0); a1 = fmaf(n6, bhi(v60), a1);
        a2 = fmaf(n6, blo(v61), a2); a3 = fmaf(n6, bhi(v61), a3);
        a4 = fmaf(n6, blo(v62), a4); a5 = fmaf(n6, bhi(v62), a5);
        a0 = fmaf(n7, blo(v70), a0); a1 = fmaf(n7, bhi(v70), a1);
        a2 = fmaf(n7, blo(v71), a2); a3 = fmaf(n7, bhi(v71), a3);
        a4 = fmaf(n7, blo(v72), a4); a5 = fmaf(n7, bhi(v72), a5);
    }
    for (; e + 3 < e1; e += 4) {
        int2 p0 = eb[e], p1 = eb[e + 1], p2 = eb[e + 2], p3 = eb[e + 3];
        const uint32* q0 = fp + p0.x * 192;
        const uint32* q1 = fp + p1.x * 192;
        const uint32* q2 = fp + p2.x * 192;
        const uint32* q3 = fp + p3.x * 192;
        uint32 v00 = q0[0], v01 = q0[1], v02 = q0[2];
        uint32 v10 = q1[0], v11 = q1[1], v12 = q1[2];
        uint32 v20 = q2[0], v21 = q2[1], v22 = q2[2];
        uint32 v30 = q3[0], v31 = q3[1], v32 = q3[2];
        float n0 = __int_as_float(p0.y), n1 = __int_as_float(p1.y);
        float n2 = __int_as_float(p2.y), n3 = __int_as_float(p3.y);
        a0 = fmaf(n0, blo(v00), a0); a1 = fmaf(n0, bhi(v00), a1);
        a2 = fmaf(n0, blo(v01), a2); a3 = fmaf(n0, bhi(v01), a3);
        a4 = fmaf(n0, blo(v02), a4); a5 = fmaf(n0, bhi(v02), a5);
        a0 = fmaf(n1, blo(v10), a0); a1 = fmaf(n1, bhi(v10), a1);
        a2 = fmaf(n1, blo(v11), a2); a3 = fmaf(n1, bhi(v11), a3);
        a4 = fmaf(n1, blo(v12), a4); a5 = fmaf(n1, bhi(v12), a5);
        a0 = fmaf(n2, blo(v20), a0); a1 = fmaf(n2, bhi(v20), a1);
        a2 = fmaf(n2, blo(v21), a2); a3 = fmaf(n2, bhi(v21), a3);
        a4 = fmaf(n2, blo(v22), a4); a5 = fmaf(n2, bhi(v22), a5);
        a0 = fmaf(n3, blo(v30), a0); a1 = fmaf(n3, bhi(v30), a1);
        a2 = fmaf(n3, blo(v31), a2); a3 = fmaf(n3, bhi(v31), a3);
        a4 = fmaf(n3, blo(v32), a4); a5 = fmaf(n3, bhi(v32), a5);
    }
    for (; e < e1; ++e) {
        int2 p0 = eb[e];
        const uint32* q0 = fp + p0.x * 192;
        uint32 v00 = q0[0], v01 = q0[1], v02 = q0[2];
        float n0 = __int_as_float(p0.y);
        a0 = fmaf(n0, blo(v00), a0); a1 = fmaf(n0, bhi(v00), a1);
        a2 = fmaf(n0, blo(v01), a2); a3 = fmaf(n0, bhi(v01), a3);
        a4 = fmaf(n0, blo(v02), a4); a5 = fmaf(n0, bhi(v02), a5);
    }

    uint32* op = AggU + d * 192 + 3 * l;
    op[0] = pk2(a0, a1);
    op[1] = pk2(a2, a3);
    op[2] = pk2(a4, a5);
}

// rh record R[n][128 u32] (bf16 slot = b*64 + ch), lane l covers u32 slots 2l,2l+1.
// writes Arh bf16 into Agg h-region (node-major): u32 slot d*192 + 64 + b*32 + cp
__global__ __launch_bounds__(256) void k_gather_rh(
    const int* __restrict__ rowptr, const int2* __restrict__ eb,
    const float* __restrict__ dinv, const uint32* __restrict__ R,
    uint32* __restrict__ AggU) {

    int l = threadIdx.x & 63;
    int d = __builtin_amdgcn_readfirstlane(blockIdx.x * 4 + (threadIdx.x >> 6));
    float dv = dinv[d];
    float s2 = dv * dv;

    const uint32* rp = R + 2 * l;
    uint2 sv = *(const uint2*)(rp + d * 128);
    float a0 = s2 * blo(sv.x), a1 = s2 * bhi(sv.x);
    float a2 = s2 * blo(sv.y), a3 = s2 * bhi(sv.y);

    int e  = rowptr[d];
    int e1 = rowptr[d + 1];

    for (; e + 7 < e1; e += 8) {
        int2 p0 = eb[e],     p1 = eb[e + 1], p2 = eb[e + 2], p3 = eb[e + 3];
        int2 p4 = eb[e + 4], p5 = eb[e + 5], p6 = eb[e + 6], p7 = eb[e + 7];
        uint2 v0 = *(const uint2*)(rp + p0.x * 128);
        uint2 v1 = *(const uint2*)(rp + p1.x * 128);
        uint2 v2 = *(const uint2*)(rp + p2.x * 128);
        uint2 v3 = *(const uint2*)(rp + p3.x * 128);
        uint2 v4 = *(const uint2*)(rp + p4.x * 128);
        uint2 v5 = *(const uint2*)(rp + p5.x * 128);
        uint2 v6 = *(const uint2*)(rp + p6.x * 128);
        uint2 v7 = *(const uint2*)(rp + p7.x * 128);
        float n0 = __int_as_float(p0.y), n1 = __int_as_float(p1.y);
        float n2 = __int_as_float(p2.y), n3 = __int_as_float(p3.y);
        float n4 = __int_as_float(p4.y), n5 = __int_as_float(p5.y);
        float n6 = __int_as_float(p6.y), n7 = __int_as_float(p7.y);
        a0 = fmaf(n0, blo(v0.x), a0); a1 = fmaf(n0, bhi(v0.x), a1);
        a2 = fmaf(n0, blo(v0.y), a2); a3 = fmaf(n0, bhi(v0.y), a3);
        a0 = fmaf(n1, blo(v1.x), a0); a1 = fmaf(n1, bhi(v1.x), a1);
        a2 = fmaf(n1, blo(v1.y), a2); a3 = fmaf(n1, bhi(v1.y), a3);
        a0 = fmaf(n2, blo(v2.x), a0); a1 = fmaf(n2, bhi(v2.x), a1);
        a2 = fmaf(n2, blo(v2.y), a2); a3 = fmaf(n2, bhi(v2.y), a3);
        a0 = fmaf(n3, blo(v3.x), a0); a1 = fmaf(n3, bhi(v3.x), a1);
        a2 = fmaf(n3, blo(v3.y), a2); a3 = fmaf(n3, bhi(v3.y), a3);
        a0 = fmaf(n4, blo(v4.x), a0); a1 = fmaf(n4, bhi(v4.x), a1);
        a2 = fmaf(n4, blo(v4.y), a2); a3 = fmaf(n4, bhi(v4.y), a3);
        a0 = fmaf(n5, blo(v5.x), a0); a1 = fmaf(n5, bhi(v5.x), a1);
        a2 = fmaf(n5, blo(v5.y), a2); a3 = fmaf(n5, bhi(v5.y), a3);
        a0 = fmaf(n6, blo(v6.x), a0); a1 = fmaf(n6, bhi(v6.x), a1);
        a2 = fmaf(n6, blo(v6.y), a2); a3 = fmaf(n6, bhi(v6.y), a3);
        a0 = fmaf(n7, blo(v7.x), a0); a1 = fmaf(n7, bhi(v7.x), a1);
        a2 = fmaf(n7, blo(v7.y), a2); a3 = fmaf(n7, bhi(v7.y), a3);
    }
    for (; e + 3 < e1; e += 4) {
        int2 p0 = eb[e], p1 = eb[e + 1], p2 = eb[e + 2], p3 = eb[e + 3];
        uint2 v0 = *(const uint2*)(rp + p0.x * 128);
        uint2 v1 = *(const uint2*)(rp + p1.x * 128);
        uint2 v2 = *(const uint2*)(rp + p2.x * 128);
        uint2 v3 = *(const uint2*)(rp + p3.x * 128);
        float n0 = __int_as_float(p0.y), n1 = __int_as_float(p1.y);
        float n2 = __int_as_float(p2.y), n3 = __int_as_float(p3.y);
        a0 = fmaf(n0, blo(v0.x), a0); a1 = fmaf(n0, bhi(v0.x), a1);
        a2 = fmaf(n0, blo(v0.y), a2); a3 = fmaf(n0, bhi(v0.y), a3);
        a0 = fmaf(n1, blo(v1.x), a0); a1 = fmaf(n1, bhi(v1.x), a1);
        a2 = fmaf(n1, blo(v1.y), a2); a3 = fmaf(n1, bhi(v1.y), a3);
        a0 = fmaf(n2, blo(v2.x), a0); a1 = fmaf(n2, bhi(v2.x), a1);
        a2 = fmaf(n2, blo(v2.y), a2); a3 = fmaf(n2, bhi(v2.y), a3);
        a0 = fmaf(n3, blo(v3.x), a0); a1 = fmaf(n3, bhi(v3.x), a1);
        a2 = fmaf(n3, blo(v3.y), a2); a3 = fmaf(n3, bhi(v3.y), a3);
    }
    for (; e < e1; ++e) {
        int2 p0 = eb[e];
        uint2 v0 = *(const uint2*)(rp + p0.x * 128);
        float n0 = __int_as_float(p0.y);
        a0 = fmaf(n0, blo(v0.x), a0); a1 = fmaf(n0, bhi(v0.x), a1);
        a2 = fmaf(n0, blo(v0.y), a2); a3 = fmaf(n0, bhi(v0.y), a3);
    }

    *(uint2*)&AggU[d * 192 + 64 + (l >> 4) * 32 + ((2 * l) & 31)] =
        make_uint2(pk2(a0, a1), pk2(a2, a3));
}

// ================= dense kernels (MFMA, weights in registers, grid-stride) =================
// h is read as bf16 from the F record (F stays alive; R is a separate buffer).

__global__ __launch_bounds__(256) void k_zr(
    const uint32* __restrict__ AggU, const uint32* __restrict__ F,
    const uint32* __restrict__ WB, const float* __restrict__ BS,
    uint2* __restrict__ Zb2, ushort_t* __restrict__ R16) {

    int l  = threadIdx.x & 63;
    int wv = blockIdx.x * 4 + (threadIdx.x >> 6);    // 0..DWAVES-1
    int lr = l & 15, lg = l >> 4;

    const bf16x8* wz = (const bf16x8*)WB;
    const bf16x8* wr = (const bf16x8*)(WB + 3072);
    bf16x8 wzf[12], wrf[12];
    #pragma unroll
    for (int f = 0; f < 12; ++f) { wzf[f] = wz[f * 64 + l]; wrf[f] = wr[f * 64 + l]; }
    float bz[4], br[4];
    #pragma unroll
    for (int ct = 0; ct < 4; ++ct) {
        bz[ct] = BS[ct * 16 + lr];
        br[ct] = BS[64 + ct * 16 + lr];
    }

    for (int t = wv; t < NTILE; t += DWAVES) {
        int bb = t / TPB, nt = t - bb * TPB;
        const uint32* base = AggU + (nt * 16 + lr) * 192;
        bf16x8 af0 = *(const bf16x8*)(base + bb * 16 + lg * 4);
        bf16x8 af1 = *(const bf16x8*)(base + 64 + bb * 32 + lg * 4);
        bf16x8 af2 = *(const bf16x8*)(base + 64 + bb * 32 + 16 + lg * 4);

        f32x4 az[4], ar[4];
        #pragma unroll
        for (int c = 0; c < 4; ++c) { az[c] = (f32x4){0,0,0,0}; ar[c] = (f32x4){0,0,0,0}; }

        #pragma unroll
        for (int ct = 0; ct < 4; ++ct) {
            az[ct] = __builtin_amdgcn_mfma_f32_16x16x32_bf16(af0, wzf[0*4+ct], az[ct], 0,0,0);
            ar[ct] = __builtin_amdgcn_mfma_f32_16x16x32_bf16(af0, wrf[0*4+ct], ar[ct], 0,0,0);
            az[ct] = __builtin_amdgcn_mfma_f32_16x16x32_bf16(af1, wzf[1*4+ct], az[ct], 0,0,0);
            ar[ct] = __builtin_amdgcn_mfma_f32_16x16x32_bf16(af1, wrf[1*4+ct], ar[ct], 0,0,0);
            az[ct] = __builtin_amdgcn_mfma_f32_16x16x32_bf16(af2, wzf[2*4+ct], az[ct], 0,0,0);
            ar[ct] = __builtin_amdgcn_mfma_f32_16x16x32_bf16(af2, wrf[2*4+ct], ar[ct], 0,0,0);
        }

        int node0 = nt * 16;
        #pragma unroll
        for (int ct = 0; ct < 4; ++ct) {
            int ch = ct * 16 + lr;
            uint32 z01, z23;
            #pragma unroll
            for (int rr = 0; rr < 4; ++rr) {
                int node = node0 + lg * 4 + rr;
                float zv = sigm(az[ct][rr] + bz[ct]);
                float rv = sigm(ar[ct][rr] + br[ct]);
                uint32 hu = F[node * 192 + 64 + bb * 32 + ct * 8 + (lr >> 1)];
                float hv = (lr & 1) ? bhi(hu) : blo(hu);
                uint32 zb = (__float_as_uint(zv) + 0x7FFFu + ((__float_as_uint(zv) >> 16) & 1u)) >> 16;
                if (rr == 0) z01 = zb;
                else if (rr == 1) z01 |= zb << 16;
                else if (rr == 2) z23 = zb;
                else z23 |= zb << 16;
                float rh = rv * hv;
                uint32 ru = __float_as_uint(rh);
                R16[node * 256 + bb * 64 + ch] =
                    (ushort_t)((ru + 0x7FFFu + ((ru >> 16) & 1u)) >> 16);
            }
            Zb2[(t * 4 + ct) * 64 + l] = make_uint2(z01, z23);
        }
    }
}

__global__ __launch_bounds__(256) void k_final(
    const uint32* __restrict__ AggU, const uint32* __restrict__ F,
    const uint32* __restrict__ WB, const float* __restrict__ BS,
    const uint2* __restrict__ Zb2, float* __restrict__ out) {

    int l  = threadIdx.x & 63;
    int wv = blockIdx.x * 4 + (threadIdx.x >> 6);
    int lr = l & 15, lg = l >> 4;

    const bf16x8* wh = (const bf16x8*)(WB + 6144);
    bf16x8 whf[12];
    #pragma unroll
    for (int f = 0; f < 12; ++f) whf[f] = wh[f * 64 + l];
    float bs[4];
    #pragma unroll
    for (int ct = 0; ct < 4; ++ct) bs[ct] = BS[128 + ct * 16 + lr];

    for (int t = wv; t < NTILE; t += DWAVES) {
        int bb = t / TPB, nt = t - bb * TPB;
        const uint32* base = AggU + (nt * 16 + lr) * 192;
        bf16x8 af0 = *(const bf16x8*)(base + bb * 16 + lg * 4);
        bf16x8 af1 = *(const bf16x8*)(base + 64 + bb * 32 + lg * 4);
        bf16x8 af2 = *(const bf16x8*)(base + 64 + bb * 32 + 16 + lg * 4);

        f32x4 ac[4];
        #pragma unroll
        for (int c = 0; c < 4; ++c) ac[c] = (f32x4){0,0,0,0};

        #pragma unroll
        for (int ct = 0; ct < 4; ++ct) {
            ac[ct] = __builtin_amdgcn_mfma_f32_16x16x32_bf16(af0, whf[0*4+ct], ac[ct], 0,0,0);
            ac[ct] = __builtin_amdgcn_mfma_f32_16x16x32_bf16(af1, whf[1*4+ct], ac[ct], 0,0,0);
            ac[ct] = __builtin_amdgcn_mfma_f32_16x16x32_bf16(af2, whf[2*4+ct], ac[ct], 0,0,0);
        }

        int node0 = nt * 16;
        #pragma unroll
        for (int ct = 0; ct < 4; ++ct) {
            int ch = ct * 16 + lr;
            uint2 zv2 = Zb2[(t * 4 + ct) * 64 + l];
            #pragma unroll
            for (int rr = 0; rr < 4; ++rr) {
                int node = node0 + lg * 4 + rr;
                int off  = (bb * NN + node) * 64 + ch;
                float hh = tanhf(ac[ct][rr] + bs[ct]);
                float zv = (rr == 0) ? blo(zv2.x) : (rr == 1) ? bhi(zv2.x)
                         : (rr == 2) ? blo(zv2.y) : bhi(zv2.y);
                uint32 hu = F[node * 192 + 64 + bb * 32 + ct * 8 + (lr >> 1)];
                float hv = (lr & 1) ? bhi(hu) : blo(hu);
                out[off] = (1.0f - zv) * hv + zv * hh;
            }
        }
    }
}

// ================= host launch =================

extern "C" void kernel_launch(void* const* d_in, const int* in_sizes, int n_in,
                              void* d_out, int out_size, void* d_ws, size_t ws_size,
                              hipStream_t stream) {
    const float* x   = (const float*)d_in[0];
    const float* h   = (const float*)d_in[1];
    const int*   ei  = (const int*)d_in[2];
    const float* ew  = (const float*)d_in[3];
    const float* Wuz = (const float*)d_in[4];
    const float* buz = (const float*)d_in[5];
    const float* Whz = (const float*)d_in[6];
    const float* bhz = (const float*)d_in[7];
    const float* Wur = (const float*)d_in[8];
    const float* bur = (const float*)d_in[9];
    const float* Whr = (const float*)d_in[10];
    const float* bhr = (const float*)d_in[11];
    const float* Wuh = (const float*)d_in[12];
    const float* buh = (const float*)d_in[13];
    const float* Whh = (const float*)d_in[14];
    const float* bhh = (const float*)d_in[15];
    float* out = (float*)d_out;

    // ws layout (4B words), total 33,711,808 words = 134.85 MB
    // Zb region [0 .. 6.4M) also hosts degcnt/tmp/cursor/parts (all dead before
    // k_zr writes Zb).
    float*    w      = (float*)d_ws;
    u64*      degcnt = (u64*)w;                       // 102,400 (dead after scan3)
    int*      tmp    = (int*)(w + 102400);            // 51,200 (dead after scan3)
    int*      cursor = (int*)(w + 153600);            // 51,200 (dead after bucket)
    int*      parts  = (int*)(w + 204800);            // 256    (dead after scan3)
    uint2*    Zb2    = (uint2*)w;                     // 6,400,000 words (k_zr onward)
    float*    dinv   = w + 6400000;                   // 51,200
    int*      rowptr = (int*)(w + 6451200);           // 51,200
    int2*     eb     = (int2*)(w + 6502400);          // 1,600,000
    uint32*   F      = (uint32*)(w + 8102400);        // 9,600,000 (alive to the end)
    uint32*   AggU   = (uint32*)(w + 17702400);       // 9,600,000
    uint32*   R      = (uint32*)(w + 27302400);       // 6,400,000
    uint32*   WB     = (uint32*)(w + 33702400);       // 9,216
    float*    BS     = (float*)(w + 33711616);        // 192

    k_prep<<<2048, 256, 0, stream>>>((const float4*)x, (const float4*)h,
                                     Wuz, Whz, Wur, Whr, Wuh, Whh,
                                     buz, bhz, bur, bhr, buh, bhh,
                                     (uint2*)F, degcnt, WB, BS);
    k_degcnt<<<2048, 256, 0, stream>>>(ei, ew, degcnt);

    k_scan1<<<NBLK, 256, 0, stream>>>(degcnt, tmp, parts);
    k_scan3<<<NBLK, 256, 0, stream>>>(tmp, degcnt, parts, rowptr, cursor, dinv);

    k_bucket<<<2048, 256, 0, stream>>>(ei, ew, dinv, cursor, eb);

    k_gather_xh<<<NN / 4, 256, 0, stream>>>(rowptr, eb, dinv, F, AggU);

    k_zr<<<DWAVES / 4, 256, 0, stream>>>(AggU, F, WB, BS, Zb2, (ushort_t*)R);

    k_gather_rh<<<NN / 4, 256, 0, stream>>>(rowptr, eb, dinv, R, AggU);

    k_final<<<DWAVES / 4, 256, 0, stream>>>(AggU, F, WB, BS, Zb2, out);
}

// Round 11
// 319.838 us; speedup vs baseline: 1.1935x; 1.0137x over previous
//
#include <hip/hip_runtime.h>
#include <math.h>

#define NN 50000
#define CIN 32
#define HD  64
#define NE  800000
#define NB  4
#define NBLK 196    // ceil(NN/256) scan blocks
#define NTILE 12500 // 200000 pairs / 16
#define TPB   3125  // tiles per batch (NN/16)
#define DWAVES 4096 // dense kernels: 1024 blocks * 4 waves

typedef unsigned int uint32;
typedef unsigned short ushort_t;
typedef unsigned long long u64;
typedef __attribute__((ext_vector_type(8))) short bf16x8;
typedef __attribute__((ext_vector_type(4))) float f32x4;

// ---- bf16 pack/unpack helpers (RNE) ----
__device__ __forceinline__ uint32 pk2(float a, float b) {
    uint32 ua = __float_as_uint(a), ub = __float_as_uint(b);
    uint32 ra = (ua + 0x7FFFu + ((ua >> 16) & 1u)) >> 16;
    uint32 rb = (ub + 0x7FFFu + ((ub >> 16) & 1u)) >> 16;
    return ra | (rb << 16);
}
__device__ __forceinline__ float blo(uint32 v) { return __uint_as_float(v << 16); }
__device__ __forceinline__ float bhi(uint32 v) { return __uint_as_float(v & 0xFFFF0000u); }
__device__ __forceinline__ float sigm(float v) { return 1.0f / (1.0f + __expf(-v)); }

// ================= prepass (pure streaming, no atomics) =================
// F[n][192 u32] record: j in [0,64): x (b=j>>4, ch-pair j&15); j in [64,192): h
// (j'=j-64, b=j'>>5, ch-pair j'&31). Record-linear: thread t owns uint2 slot t,
// so writes are perfectly dense; reads are 6 contiguous segments per record.

__global__ void k_prep(const float4* __restrict__ x4, const float4* __restrict__ h4,
                       const float* __restrict__ Wuz, const float* __restrict__ Whz,
                       const float* __restrict__ Wur, const float* __restrict__ Whr,
                       const float* __restrict__ Wuh, const float* __restrict__ Whh,
                       const float* __restrict__ buz, const float* __restrict__ bhz,
                       const float* __restrict__ bur, const float* __restrict__ bhr,
                       const float* __restrict__ buh, const float* __restrict__ bhh,
                       uint2* __restrict__ F2, u64* __restrict__ degcnt,
                       uint32* __restrict__ WB, float* __restrict__ BS) {
    int stride = gridDim.x * blockDim.x;
    int tid = blockIdx.x * blockDim.x + threadIdx.x;

    if (tid < NN) degcnt[tid] = (1ull << 24);   // self-loop weight 1.0 fixed point

    if (tid < 9216) {   // weight frags (same (lane,elem)->k bijection as A packing)
        int g = tid / 3072, rem = tid - g * 3072;
        int kt = rem >> 10, r2 = rem & 1023;
        int ct = r2 >> 8, r3 = r2 & 255;
        int l = r3 >> 2, jp = r3 & 3;
        int k = kt * 32 + ((l >> 4) << 3) + 2 * jp;
        int ch = ct * 16 + (l & 15);
        const float* Wu = (g == 0) ? Wuz : (g == 1) ? Wur : Wuh;
        const float* Wh = (g == 0) ? Whz : (g == 1) ? Whr : Whh;
        float w0 = (k < 32) ? Wu[k * 64 + ch] : Wh[(k - 32) * 64 + ch];
        int k1 = k + 1;
        float w1 = (k1 < 32) ? Wu[k1 * 64 + ch] : Wh[(k1 - 32) * 64 + ch];
        WB[tid] = pk2(w0, w1);
    }
    if (tid < 192) {
        int g = tid >> 6, c = tid & 63;
        const float* bu = (g == 0) ? buz : (g == 1) ? bur : buh;
        const float* bh = (g == 0) ? bhz : (g == 1) ? bhr : bhh;
        BS[tid] = bu[c] + bh[c];
    }

    // record-linear conversion: NN*96 uint2 slots
    for (int t = tid; t < NN * 96; t += stride) {
        int n = t / 96, slot = t - n * 96;
        float4 v;
        if (slot < 32) {           // x part: b = slot>>3, cq = slot&7
            v = x4[(((slot >> 3) * NN) + n) * 8 + (slot & 7)];
        } else {                   // h part: b = (slot-32)>>4, cq = (slot-32)&15
            int s2 = slot - 32;
            v = h4[(((s2 >> 4) * NN) + n) * 16 + (s2 & 15)];
        }
        F2[t] = make_uint2(pk2(v.x, v.y), pk2(v.z, v.w));
    }
}

// one u64 atomic per edge: count in bits >=40, weight in 2^-24 fixed point low bits
__global__ void k_degcnt(const int* __restrict__ ei, const float* __restrict__ ew,
                         u64* __restrict__ degcnt) {
    int stride = gridDim.x * blockDim.x;
    for (int e = blockIdx.x * blockDim.x + threadIdx.x; e < NE; e += stride) {
        int d = ei[NE + e];
        u64 val = (1ull << 40) + (u64)(uint32)(ew[e] * 16777216.0f + 0.5f);
        atomicAdd(&degcnt[d], val);
    }
}

// ---- scan of counts -> rowptr, cursor; dinv (scan2 folded into scan3) ----

__global__ void k_scan1(const u64* __restrict__ degcnt, int* __restrict__ tmp,
                        int* __restrict__ partials) {
    __shared__ int lds[256];
    int i = blockIdx.x * 256 + threadIdx.x;
    int v = (i < NN) ? (int)(degcnt[i] >> 40) : 0;
    lds[threadIdx.x] = v;
    __syncthreads();
    for (int off = 1; off < 256; off <<= 1) {
        int t = (threadIdx.x >= off) ? lds[threadIdx.x - off] : 0;
        __syncthreads();
        lds[threadIdx.x] += t;
        __syncthreads();
    }
    if (i < NN) tmp[i] = lds[threadIdx.x];
    if (threadIdx.x == 255) partials[blockIdx.x] = lds[255];
}

// each block locally exclusive-scans partials[NBLK] in LDS (no global mutation)
__global__ void k_scan3(const int* __restrict__ tmp, const u64* __restrict__ degcnt,
                        const int* __restrict__ partials,
                        int* __restrict__ rowptr, int* __restrict__ cursor,
                        float* __restrict__ dinv) {
    __shared__ int lds[256];
    int v = (threadIdx.x < NBLK) ? partials[threadIdx.x] : 0;
    lds[threadIdx.x] = v;
    __syncthreads();
    for (int off = 1; off < 256; off <<= 1) {
        int t = (threadIdx.x >= off) ? lds[threadIdx.x - off] : 0;
        __syncthreads();
        lds[threadIdx.x] += t;
        __syncthreads();
    }
    int i = blockIdx.x * blockDim.x + threadIdx.x;
    if (i < NN) {
        int blk = i >> 8;
        int ex = (blk > 0) ? lds[blk - 1] : 0;
        u64 dc = degcnt[i];
        int cnt = (int)(dc >> 40);
        int inc = tmp[i] + ex;
        rowptr[i + 1] = inc;
        cursor[i] = inc - cnt;
        if (i == 0) rowptr[0] = 0;
        float dg = (float)(dc & 0xFFFFFFFFFFull) * 5.9604644775390625e-08f;
        dinv[i] = (dg > 0.0f) ? rsqrtf(fmaxf(dg, 1e-12f)) : 0.0f;
    }
}

__global__ void k_bucket(const int* __restrict__ ei, const float* __restrict__ ew,
                         const float* __restrict__ dinv,
                         int* __restrict__ cursor, int2* __restrict__ eb) {
    int stride = gridDim.x * blockDim.x;
    for (int e = blockIdx.x * blockDim.x + threadIdx.x; e < NE; e += stride) {
        int s = ei[e], d = ei[NE + e];
        float nrm = dinv[s] * ew[e] * dinv[d];
        int pos = atomicAdd(&cursor[d], 1);
        eb[pos] = make_int2(s, __float_as_int(nrm));
    }
}

// ================= gathers =================
// one wave per dst node; lane l covers u32 slots 3l..3l+2 of the 192-u32 record.
// Agg layout == F layout (node-major), so writes are 3 consecutive dwords.

__global__ __launch_bounds__(256) void k_gather_xh(
    const int* __restrict__ rowptr, const int2* __restrict__ eb,
    const float* __restrict__ dinv, const uint32* __restrict__ F,
    uint32* __restrict__ AggU) {

    int l = threadIdx.x & 63;
    int d = __builtin_amdgcn_readfirstlane(blockIdx.x * 4 + (threadIdx.x >> 6));
    float dv = dinv[d];
    float s2 = dv * dv;

    const uint32* fp = F + 3 * l;
    const uint32* sp = fp + d * 192;
    uint32 u0 = sp[0], u1 = sp[1], u2 = sp[2];
    float a0 = s2 * blo(u0), a1 = s2 * bhi(u0);
    float a2 = s2 * blo(u1), a3 = s2 * bhi(u1);
    float a4 = s2 * blo(u2), a5 = s2 * bhi(u2);

    int e  = rowptr[d];
    int e1 = rowptr[d + 1];

    for (; e + 7 < e1; e += 8) {
        int2 p0 = eb[e],     p1 = eb[e + 1], p2 = eb[e + 2], p3 = eb[e + 3];
        int2 p4 = eb[e + 4], p5 = eb[e + 5], p6 = eb[e + 6], p7 = eb[e + 7];
        const uint32* q0 = fp + p0.x * 192;
        const uint32* q1 = fp + p1.x * 192;
        const uint32* q2 = fp + p2.x * 192;
        const uint32* q3 = fp + p3.x * 192;
        const uint32* q4 = fp + p4.x * 192;
        const uint32* q5 = fp + p5.x * 192;
        const uint32* q6 = fp + p6.x * 192;
        const uint32* q7 = fp + p7.x * 192;
        uint32 v00 = q0[0], v01 = q0[1], v02 = q0[2];
        uint32 v10 = q1[0], v11 = q1[1], v12 = q1[2];
        uint32 v20 = q2[0], v21 = q2[1], v22 = q2[2];
        uint32 v30 = q3[0], v31 = q3[1], v32 = q3[2];
        uint32 v40 = q4[0], v41 = q4[1], v42 = q4[2];
        uint32 v50 = q5[0], v51 = q5[1], v52 = q5[2];
        uint32 v60 = q6[0], v61 = q6[1], v62 = q6[2];
        uint32 v70 = q7[0], v71 = q7[1], v72 = q7[2];
        float n0 = __int_as_float(p0.y), n1 = __int_as_float(p1.y);
        float n2 = __int_as_float(p2.y), n3 = __int_as_float(p3.y);
        float n4 = __int_as_float(p4.y), n5 = __int_as_float(p5.y);
        float n6 = __int_as_float(p6.y), n7 = __int_as_float(p7.y);
        a0 = fmaf(n0, blo(v00), a0); a1 = fmaf(n0, bhi(v00), a1);
        a2 = fmaf(n0, blo(v01), a2); a3 = fmaf(n0, bhi(v01), a3);
        a4 = fmaf(n0, blo(v02), a4); a5 = fmaf(n0, bhi(v02), a5);
        a0 = fmaf(n1, blo(v10), a0); a1 = fmaf(n1, bhi(v10), a1);
        a2 = fmaf(n1, blo(v11), a2); a3 = fmaf(n1, bhi(v11), a3);
        a4 = fmaf(n1, blo(v12), a4); a5 = fmaf(n1, bhi(v12), a5);
        a0 = fmaf(n2, blo(v20), a0); a1 = fmaf(n2, bhi(v20), a1);
        a2 = fmaf(n2, blo(v21), a2); a3 = fmaf(n2, bhi(v21), a3);
        a4 = fmaf(n2, blo(v22), a4); a5 = fmaf(n2, bhi(v22), a5);
        a0 = fmaf(n3, blo(v30), a0); a1 = fmaf(n3, bhi(v30), a1);
        a2 = fmaf(n3, blo(v31), a2); a3 = fmaf(n3, bhi(v31), a3);
        a4 = fmaf(n3, blo(v32), a4); a5 = fmaf(n3, bhi(v32), a5);
        a0 = fmaf(n4, blo(v40), a0); a1 = fmaf(n4, bhi(v40), a1);
        a2 = fmaf(n4, blo(v41), a2); a3 = fmaf(n4, bhi(v41), a3);
        a4 = fmaf(n4, blo(v42), a4); a5 = fmaf(n4, bhi(v42), a5);
        a0 = fmaf(n5, blo(v50), a0); a1 = fmaf(n5, bhi(v50), a1);
        a2 = fmaf(n5, blo(v51), a2); a3 = fmaf(n5, bhi(v51), a3);
        a4 = fmaf(n5, blo(v52), a4); a5 = fmaf(n5, bhi(v52), a5);
        a0 = fmaf(n6, blo(v60), a0); a1 = fmaf(n6, bhi(v60), a1);
        a2 = fmaf(n6, blo(v61), a2); a3 = fmaf(n6, bhi(v61), a3);
        a4 = fmaf(n6, blo(v62), a4); a5 = fmaf(n6, bhi(v62), a5);
        a0 = fmaf(n7, blo(v70), a0); a1 = fmaf(n7, bhi(v70), a1);
        a2 = fmaf(n7, blo(v71), a2); a3 = fmaf(n7, bhi(v71), a3);
        a4 = fmaf(n7, blo(v72), a4); a5 = fmaf(n7, bhi(v72), a5);
    }
    for (; e + 3 < e1; e += 4) {
        int2 p0 = eb[e], p1 = eb[e + 1], p2 = eb[e + 2], p3 = eb[e + 3];
        const uint32* q0 = fp + p0.x * 192;
        const uint32* q1 = fp + p1.x * 192;
        const uint32* q2 = fp + p2.x * 192;
        const uint32* q3 = fp + p3.x * 192;
        uint32 v00 = q0[0], v01 = q0[1], v02 = q0[2];
        uint32 v10 = q1[0], v11 = q1[1], v12 = q1[2];
        uint32 v20 = q2[0], v21 = q2[1], v22 = q2[2];
        uint32 v30 = q3[0], v31 = q3[1], v32 = q3[2];
        float n0 = __int_as_float(p0.y), n1 = __int_as_float(p1.y);
        float n2 = __int_as_float(p2.y), n3 = __int_as_float(p3.y);
        a0 = fmaf(n0, blo(v00), a0); a1 = fmaf(n0, bhi(v00), a1);
        a2 = fmaf(n0, blo(v01), a2); a3 = fmaf(n0, bhi(v01), a3);
        a4 = fmaf(n0, blo(v02), a4); a5 = fmaf(n0, bhi(v02), a5);
        a0 = fmaf(n1, blo(v10), a0); a1 = fmaf(n1, bhi(v10), a1);
        a2 = fmaf(n1, blo(v11), a2); a3 = fmaf(n1, bhi(v11), a3);
        a4 = fmaf(n1, blo(v12), a4); a5 = fmaf(n1, bhi(v12), a5);
        a0 = fmaf(n2, blo(v20), a0); a1 = fmaf(n2, bhi(v20), a1);
        a2 = fmaf(n2, blo(v21), a2); a3 = fmaf(n2, bhi(v21), a3);
        a4 = fmaf(n2, blo(v22), a4); a5 = fmaf(n2, bhi(v22), a5);
        a0 = fmaf(n3, blo(v30), a0); a1 = fmaf(n3, bhi(v30), a1);
        a2 = fmaf(n3, blo(v31), a2); a3 = fmaf(n3, bhi(v31), a3);
        a4 = fmaf(n3, blo(v32), a4); a5 = fmaf(n3, bhi(v32), a5);
    }
    for (; e < e1; ++e) {
        int2 p0 = eb[e];
        const uint32* q0 = fp + p0.x * 192;
        uint32 v00 = q0[0], v01 = q0[1], v02 = q0[2];
        float n0 = __int_as_float(p0.y);
        a0 = fmaf(n0, blo(v00), a0); a1 = fmaf(n0, bhi(v00), a1);
        a2 = fmaf(n0, blo(v01), a2); a3 = fmaf(n0, bhi(v01), a3);
        a4 = fmaf(n0, blo(v02), a4); a5 = fmaf(n0, bhi(v02), a5);
    }

    uint32* op = AggU + d * 192 + 3 * l;
    op[0] = pk2(a0, a1);
    op[1] = pk2(a2, a3);
    op[2] = pk2(a4, a5);
}

// rh record R[n][128 u32] (bf16 slot = b*64 + ch), lane l covers u32 slots 2l,2l+1.
// writes Arh bf16 into Agg h-region (node-major): u32 slot d*192 + 64 + b*32 + cp
__global__ __launch_bounds__(256) void k_gather_rh(
    const int* __restrict__ rowptr, const int2* __restrict__ eb,
    const float* __restrict__ dinv, const uint32* __restrict__ R,
    uint32* __restrict__ AggU) {

    int l = threadIdx.x & 63;
    int d = __builtin_amdgcn_readfirstlane(blockIdx.x * 4 + (threadIdx.x >> 6));
    float dv = dinv[d];
    float s2 = dv * dv;

    const uint32* rp = R + 2 * l;
    uint2 sv = *(const uint2*)(rp + d * 128);
    float a0 = s2 * blo(sv.x), a1 = s2 * bhi(sv.x);
    float a2 = s2 * blo(sv.y), a3 = s2 * bhi(sv.y);

    int e  = rowptr[d];
    int e1 = rowptr[d + 1];

    for (; e + 7 < e1; e += 8) {
        int2 p0 = eb[e],     p1 = eb[e + 1], p2 = eb[e + 2], p3 = eb[e + 3];
        int2 p4 = eb[e + 4], p5 = eb[e + 5], p6 = eb[e + 6], p7 = eb[e + 7];
        uint2 v0 = *(const uint2*)(rp + p0.x * 128);
        uint2 v1 = *(const uint2*)(rp + p1.x * 128);
        uint2 v2 = *(const uint2*)(rp + p2.x * 128);
        uint2 v3 = *(const uint2*)(rp + p3.x * 128);
        uint2 v4 = *(const uint2*)(rp + p4.x * 128);
        uint2 v5 = *(const uint2*)(rp + p5.x * 128);
        uint2 v6 = *(const uint2*)(rp + p6.x * 128);
        uint2 v7 = *(const uint2*)(rp + p7.x * 128);
        float n0 = __int_as_float(p0.y), n1 = __int_as_float(p1.y);
        float n2 = __int_as_float(p2.y), n3 = __int_as_float(p3.y);
        float n4 = __int_as_float(p4.y), n5 = __int_as_float(p5.y);
        float n6 = __int_as_float(p6.y), n7 = __int_as_float(p7.y);
        a0 = fmaf(n0, blo(v0.x), a0); a1 = fmaf(n0, bhi(v0.x), a1);
        a2 = fmaf(n0, blo(v0.y), a2); a3 = fmaf(n0, bhi(v0.y), a3);
        a0 = fmaf(n1, blo(v1.x), a0); a1 = fmaf(n1, bhi(v1.x), a1);
        a2 = fmaf(n1, blo(v1.y), a2); a3 = fmaf(n1, bhi(v1.y), a3);
        a0 = fmaf(n2, blo(v2.x), a0); a1 = fmaf(n2, bhi(v2.x), a1);
        a2 = fmaf(n2, blo(v2.y), a2); a3 = fmaf(n2, bhi(v2.y), a3);
        a0 = fmaf(n3, blo(v3.x), a0); a1 = fmaf(n3, bhi(v3.x), a1);
        a2 = fmaf(n3, blo(v3.y), a2); a3 = fmaf(n3, bhi(v3.y), a3);
        a0 = fmaf(n4, blo(v4.x), a0); a1 = fmaf(n4, bhi(v4.x), a1);
        a2 = fmaf(n4, blo(v4.y), a2); a3 = fmaf(n4, bhi(v4.y), a3);
        a0 = fmaf(n5, blo(v5.x), a0); a1 = fmaf(n5, bhi(v5.x), a1);
        a2 = fmaf(n5, blo(v5.y), a2); a3 = fmaf(n5, bhi(v5.y), a3);
        a0 = fmaf(n6, blo(v6.x), a0); a1 = fmaf(n6, bhi(v6.x), a1);
        a2 = fmaf(n6, blo(v6.y), a2); a3 = fmaf(n6, bhi(v6.y), a3);
        a0 = fmaf(n7, blo(v7.x), a0); a1 = fmaf(n7, bhi(v7.x), a1);
        a2 = fmaf(n7, blo(v7.y), a2); a3 = fmaf(n7, bhi(v7.y), a3);
    }
    for (; e + 3 < e1; e += 4) {
        int2 p0 = eb[e], p1 = eb[e + 1], p2 = eb[e + 2], p3 = eb[e + 3];
        uint2 v0 = *(const uint2*)(rp + p0.x * 128);
        uint2 v1 = *(const uint2*)(rp + p1.x * 128);
        uint2 v2 = *(const uint2*)(rp + p2.x * 128);
        uint2 v3 = *(const uint2*)(rp + p3.x * 128);
        float n0 = __int_as_float(p0.y), n1 = __int_as_float(p1.y);
        float n2 = __int_as_float(p2.y), n3 = __int_as_float(p3.y);
        a0 = fmaf(n0, blo(v0.x), a0); a1 = fmaf(n0, bhi(v0.x), a1);
        a2 = fmaf(n0, blo(v0.y), a2); a3 = fmaf(n0, bhi(v0.y), a3);
        a0 = fmaf(n1, blo(v1.x), a0); a1 = fmaf(n1, bhi(v1.x), a1);
        a2 = fmaf(n1, blo(v1.y), a2); a3 = fmaf(n1, bhi(v1.y), a3);
        a0 = fmaf(n2, blo(v2.x), a0); a1 = fmaf(n2, bhi(v2.x), a1);
        a2 = fmaf(n2, blo(v2.y), a2); a3 = fmaf(n2, bhi(v2.y), a3);
        a0 = fmaf(n3, blo(v3.x), a0); a1 = fmaf(n3, bhi(v3.x), a1);
        a2 = fmaf(n3, blo(v3.y), a2); a3 = fmaf(n3, bhi(v3.y), a3);
    }
    for (; e < e1; ++e) {
        int2 p0 = eb[e];
        uint2 v0 = *(const uint2*)(rp + p0.x * 128);
        float n0 = __int_as_float(p0.y);
        a0 = fmaf(n0, blo(v0.x), a0); a1 = fmaf(n0, bhi(v0.x), a1);
        a2 = fmaf(n0, blo(v0.y), a2); a3 = fmaf(n0, bhi(v0.y), a3);
    }

    *(uint2*)&AggU[d * 192 + 64 + (l >> 4) * 32 + ((2 * l) & 31)] =
        make_uint2(pk2(a0, a1), pk2(a2, a3));
}

// ================= dense kernels (MFMA, weights in registers, grid-stride) =================
// h is read as bf16 from the F record (F stays alive; R is a separate buffer).

__global__ __launch_bounds__(256) void k_zr(
    const uint32* __restrict__ AggU, const uint32* __restrict__ F,
    const uint32* __restrict__ WB, const float* __restrict__ BS,
    uint2* __restrict__ Zb2, ushort_t* __restrict__ R16) {

    int l  = threadIdx.x & 63;
    int wv = blockIdx.x * 4 + (threadIdx.x >> 6);    // 0..DWAVES-1
    int lr = l & 15, lg = l >> 4;

    const bf16x8* wz = (const bf16x8*)WB;
    const bf16x8* wr = (const bf16x8*)(WB + 3072);
    bf16x8 wzf[12], wrf[12];
    #pragma unroll
    for (int f = 0; f < 12; ++f) { wzf[f] = wz[f * 64 + l]; wrf[f] = wr[f * 64 + l]; }
    float bz[4], br[4];
    #pragma unroll
    for (int ct = 0; ct < 4; ++ct) {
        bz[ct] = BS[ct * 16 + lr];
        br[ct] = BS[64 + ct * 16 + lr];
    }

    for (int t = wv; t < NTILE; t += DWAVES) {
        int bb = t / TPB, nt = t - bb * TPB;
        const uint32* base = AggU + (nt * 16 + lr) * 192;
        bf16x8 af0 = *(const bf16x8*)(base + bb * 16 + lg * 4);
        bf16x8 af1 = *(const bf16x8*)(base + 64 + bb * 32 + lg * 4);
        bf16x8 af2 = *(const bf16x8*)(base + 64 + bb * 32 + 16 + lg * 4);

        f32x4 az[4], ar[4];
        #pragma unroll
        for (int c = 0; c < 4; ++c) { az[c] = (f32x4){0,0,0,0}; ar[c] = (f32x4){0,0,0,0}; }

        #pragma unroll
        for (int ct = 0; ct < 4; ++ct) {
            az[ct] = __builtin_amdgcn_mfma_f32_16x16x32_bf16(af0, wzf[0*4+ct], az[ct], 0,0,0);
            ar[ct] = __builtin_amdgcn_mfma_f32_16x16x32_bf16(af0, wrf[0*4+ct], ar[ct], 0,0,0);
            az[ct] = __builtin_amdgcn_mfma_f32_16x16x32_bf16(af1, wzf[1*4+ct], az[ct], 0,0,0);
            ar[ct] = __builtin_amdgcn_mfma_f32_16x16x32_bf16(af1, wrf[1*4+ct], ar[ct], 0,0,0);
            az[ct] = __builtin_amdgcn_mfma_f32_16x16x32_bf16(af2, wzf[2*4+ct], az[ct], 0,0,0);
            ar[ct] = __builtin_amdgcn_mfma_f32_16x16x32_bf16(af2, wrf[2*4+ct], ar[ct], 0,0,0);
        }

        int node0 = nt * 16;
        #pragma unroll
        for (int ct = 0; ct < 4; ++ct) {
            int ch = ct * 16 + lr;
            uint32 z01, z23;
            #pragma unroll
            for (int rr = 0; rr < 4; ++rr) {
                int node = node0 + lg * 4 + rr;
                float zv = sigm(az[ct][rr] + bz[ct]);
                float rv = sigm(ar[ct][rr] + br[ct]);
                uint32 hu = F[node * 192 + 64 + bb * 32 + ct * 8 + (lr >> 1)];
                float hv = (lr & 1) ? bhi(hu) : blo(hu);
                uint32 zb = (__float_as_uint(zv) + 0x7FFFu + ((__float_as_uint(zv) >> 16) & 1u)) >> 16;
                if (rr == 0) z01 = zb;
                else if (rr == 1) z01 |= zb << 16;
                else if (rr == 2) z23 = zb;
                else z23 |= zb << 16;
                float rh = rv * hv;
                uint32 ru = __float_as_uint(rh);
                R16[node * 256 + bb * 64 + ch] =
                    (ushort_t)((ru + 0x7FFFu + ((ru >> 16) & 1u)) >> 16);
            }
            Zb2[(t * 4 + ct) * 64 + l] = make_uint2(z01, z23);
        }
    }
}

__global__ __launch_bounds__(256) void k_final(
    const uint32* __restrict__ AggU, const uint32* __restrict__ F,
    const uint32* __restrict__ WB, const float* __restrict__ BS,
    const uint2* __restrict__ Zb2, float* __restrict__ out) {

    int l  = threadIdx.x & 63;
    int wv = blockIdx.x * 4 + (threadIdx.x >> 6);
    int lr = l & 15, lg = l >> 4;

    const bf16x8* wh = (const bf16x8*)(WB + 6144);
    bf16x8 whf[12];
    #pragma unroll
    for (int f = 0; f < 12; ++f) whf[f] = wh[f * 64 + l];
    float bs[4];
    #pragma unroll
    for (int ct = 0; ct < 4; ++ct) bs[ct] = BS[128 + ct * 16 + lr];

    for (int t = wv; t < NTILE; t += DWAVES) {
        int bb = t / TPB, nt = t - bb * TPB;
        const uint32* base = AggU + (nt * 16 + lr) * 192;
        bf16x8 af0 = *(const bf16x8*)(base + bb * 16 + lg * 4);
        bf16x8 af1 = *(const bf16x8*)(base + 64 + bb * 32 + lg * 4);
        bf16x8 af2 = *(const bf16x8*)(base + 64 + bb * 32 + 16 + lg * 4);

        f32x4 ac[4];
        #pragma unroll
        for (int c = 0; c < 4; ++c) ac[c] = (f32x4){0,0,0,0};

        #pragma unroll
        for (int ct = 0; ct < 4; ++ct) {
            ac[ct] = __builtin_amdgcn_mfma_f32_16x16x32_bf16(af0, whf[0*4+ct], ac[ct], 0,0,0);
            ac[ct] = __builtin_amdgcn_mfma_f32_16x16x32_bf16(af1, whf[1*4+ct], ac[ct], 0,0,0);
            ac[ct] = __builtin_amdgcn_mfma_f32_16x16x32_bf16(af2, whf[2*4+ct], ac[ct], 0,0,0);
        }

        int node0 = nt * 16;
        #pragma unroll
        for (int ct = 0; ct < 4; ++ct) {
            int ch = ct * 16 + lr;
            uint2 zv2 = Zb2[(t * 4 + ct) * 64 + l];
            #pragma unroll
            for (int rr = 0; rr < 4; ++rr) {
                int node = node0 + lg * 4 + rr;
                int off  = (bb * NN + node) * 64 + ch;
                float hh = tanhf(ac[ct][rr] + bs[ct]);
                float zv = (rr == 0) ? blo(zv2.x) : (rr == 1) ? bhi(zv2.x)
                         : (rr == 2) ? blo(zv2.y) : bhi(zv2.y);
                uint32 hu = F[node * 192 + 64 + bb * 32 + ct * 8 + (lr >> 1)];
                float hv = (lr & 1) ? bhi(hu) : blo(hu);
                out[off] = (1.0f - zv) * hv + zv * hh;
            }
        }
    }
}

// ================= host launch =================

extern "C" void kernel_launch(void* const* d_in, const int* in_sizes, int n_in,
                              void* d_out, int out_size, void* d_ws, size_t ws_size,
                              hipStream_t stream) {
    const float* x   = (const float*)d_in[0];
    const float* h   = (const float*)d_in[1];
    const int*   ei  = (const int*)d_in[2];
    const float* ew  = (const float*)d_in[3];
    const float* Wuz = (const float*)d_in[4];
    const float* buz = (const float*)d_in[5];
    const float* Whz = (const float*)d_in[6];
    const float* bhz = (const float*)d_in[7];
    const float* Wur = (const float*)d_in[8];
    const float* bur = (const float*)d_in[9];
    const float* Whr = (const float*)d_in[10];
    const float* bhr = (const float*)d_in[11];
    const float* Wuh = (const float*)d_in[12];
    const float* buh = (const float*)d_in[13];
    const float* Whh = (const float*)d_in[14];
    const float* bhh = (const float*)d_in[15];
    float* out = (float*)d_out;

    // ws layout (4B words), total 33,711,808 words = 134.85 MB
    // Zb region [0 .. 6.4M) also hosts degcnt/tmp/cursor/parts (all dead before
    // k_zr writes Zb).
    float*    w      = (float*)d_ws;
    u64*      degcnt = (u64*)w;                       // 102,400 (dead after scan3)
    int*      tmp    = (int*)(w + 102400);            // 51,200 (dead after scan3)
    int*      cursor = (int*)(w + 153600);            // 51,200 (dead after bucket)
    int*      parts  = (int*)(w + 204800);            // 256    (dead after scan3)
    uint2*    Zb2    = (uint2*)w;                     // 6,400,000 words (k_zr onward)
    float*    dinv   = w + 6400000;                   // 51,200
    int*      rowptr = (int*)(w + 6451200);           // 51,200
    int2*     eb     = (int2*)(w + 6502400);          // 1,600,000
    uint32*   F      = (uint32*)(w + 8102400);        // 9,600,000 (alive to the end)
    uint32*   AggU   = (uint32*)(w + 17702400);       // 9,600,000
    uint32*   R      = (uint32*)(w + 27302400);       // 6,400,000
    uint32*   WB     = (uint32*)(w + 33702400);       // 9,216
    float*    BS     = (float*)(w + 33711616);        // 192

    k_prep<<<2048, 256, 0, stream>>>((const float4*)x, (const float4*)h,
                                     Wuz, Whz, Wur, Whr, Wuh, Whh,
                                     buz, bhz, bur, bhr, buh, bhh,
                                     (uint2*)F, degcnt, WB, BS);
    k_degcnt<<<2048, 256, 0, stream>>>(ei, ew, degcnt);

    k_scan1<<<NBLK, 256, 0, stream>>>(degcnt, tmp, parts);
    k_scan3<<<NBLK, 256, 0, stream>>>(tmp, degcnt, parts, rowptr, cursor, dinv);

    k_bucket<<<2048, 256, 0, stream>>>(ei, ew, dinv, cursor, eb);

    k_gather_xh<<<NN / 4, 256, 0, stream>>>(rowptr, eb, dinv, F, AggU);

    k_zr<<<DWAVES / 4, 256, 0, stream>>>(AggU, F, WB, BS, Zb2, (ushort_t*)R);

    k_gather_rh<<<NN / 4, 256, 0, stream>>>(rowptr, eb, dinv, R, AggU);

    k_final<<<DWAVES / 4, 256, 0, stream>>>(AggU, F, WB, BS, Zb2, out);
}